// Round 13
// baseline (197.814 us; speedup 1.0000x reference)
//
#include <hip/hip_runtime.h>
#include <hip/hip_bf16.h>
#include <math.h>

#define B_     4
#define C_     256
#define RES_   1024
#define FEA_   3
#define LQ_    3072
#define HEADS_ 8
#define EPS_   1e-5f

typedef __bf16 bf16x8 __attribute__((ext_vector_type(8)));
typedef float  f32x16 __attribute__((ext_vector_type(16)));
typedef unsigned int uint4e __attribute__((ext_vector_type(4)));

#if __has_builtin(__builtin_amdgcn_exp2f)
#define EXP2(x) __builtin_amdgcn_exp2f(x)
#else
#define EXP2(x) exp2f(x)
#endif

__device__ __forceinline__ unsigned short bfbits(float v) {
    return __builtin_bit_cast(unsigned short, (__bf16)v);
}
__device__ __forceinline__ unsigned int pkbf(float lo, float hi2) {
    return (unsigned int)bfbits(lo) | ((unsigned int)bfbits(hi2) << 16);
}

// ---------------------------------------------------------------------------
// Fused pre-pass:
//   conv_q 4x4-token tiles   [0, 768)
//   conv_kv (K+V fused, one x-plane load, bf16 out)  [768, 1792)
//   weight cvt               [1792, 2048)
// ---------------------------------------------------------------------------
__global__ __launch_bounds__(256) void pre_kernel(
    const float* __restrict__ query, const float* __restrict__ x,
    const float* __restrict__ wq,
    const float* __restrict__ gq, const float* __restrict__ bq,
    const float* __restrict__ mq, const float* __restrict__ vq,
    const float* __restrict__ wk, const float* __restrict__ gk, const float* __restrict__ bk,
    const float* __restrict__ mk, const float* __restrict__ vk,
    const float* __restrict__ wv, const float* __restrict__ gv, const float* __restrict__ bv,
    const float* __restrict__ mv, const float* __restrict__ vv,
    const float* __restrict__ pw0, const float* __restrict__ pw1,
    const float* __restrict__ pw2, const float* __restrict__ pw3,
    __bf16* __restrict__ q_tok, __bf16* __restrict__ k_tok, __bf16* __restrict__ v_tok,
    __bf16* __restrict__ Wq, __bf16* __restrict__ Wk,
    __bf16* __restrict__ Wv, __bf16* __restrict__ Wo)
{
    __shared__ float plane[RES_];
    int blk = blockIdx.x, tid = threadIdx.x;

    if (blk < 768) {
        // ---- conv_q: one block per (b, part, 4x4 tile); thread = channel ----
        int b = blk / 192, rem = blk % 192;
        int part = rem >> 6, t = rem & 63;
        int y0 = (t >> 3) * 4, x0 = (t & 7) * 4;
        int c = tid;
        const float* wp = wq + (size_t)(part * 256 + c) * 9;
        const float* qb = query + ((size_t)b * LQ_ + (size_t)part * 1024) * 256 + c;

        float w[9];
#pragma unroll
        for (int i = 0; i < 9; ++i) w[i] = wp[i];

        float v[6][6];
#pragma unroll
        for (int iy = 0; iy < 6; ++iy) {
            int yy = y0 - 1 + iy;
#pragma unroll
            for (int ix = 0; ix < 6; ++ix) {
                int xx = x0 - 1 + ix;
                bool ok = ((unsigned)yy < 32u) && ((unsigned)xx < 32u);
                v[iy][ix] = ok ? qb[(size_t)(yy * 32 + xx) * 256] : 0.f;
            }
        }
        int gi = part * 256 + c;
        float inv = gq[gi] * rsqrtf(vq[gi] + EPS_);
        float sh  = bq[gi] - mq[gi] * inv;
#pragma unroll
        for (int yi = 0; yi < 4; ++yi) {
#pragma unroll
            for (int xi = 0; xi < 4; ++xi) {
                float acc = 0.f;
#pragma unroll
                for (int ky = 0; ky < 3; ++ky)
#pragma unroll
                    for (int kj = 0; kj < 3; ++kj)
                        acc = fmaf(w[ky * 3 + kj], v[yi + ky][xi + kj], acc);
                int l = part * 1024 + (y0 + yi) * 32 + x0 + xi;
                q_tok[((size_t)b * LQ_ + l) * 256 + c] = (__bf16)fmaf(acc, inv, sh);
            }
        }
    } else if (blk < 1792) {
        // ---- conv_kv: one block per (c, b); computes BOTH K and V convs ----
        int idx = blk - 768;
        int c = idx & 255, b = idx >> 8;
        const float* xp = x + ((size_t)b * 256 + c) * RES_;
#pragma unroll
        for (int i = 0; i < 4; ++i) plane[tid + i * 256] = xp[tid + i * 256];
        __syncthreads();

        const float* wpk = wk + (size_t)c * 9;
        const float* wpv = wv + (size_t)c * 9;
        float wkr[9], wvr[9];
#pragma unroll
        for (int i = 0; i < 9; ++i) { wkr[i] = wpk[i]; wvr[i] = wpv[i]; }
        float invK = gk[c] * rsqrtf(vk[c] + EPS_);
        float shK  = bk[c] - mk[c] * invK;
        float invV = gv[c] * rsqrtf(vv[c] + EPS_);
        float shV  = bv[c] - mv[c] * invV;
        __bf16* outK = k_tok + ((size_t)b * 256 + c) * RES_;
        __bf16* outV = v_tok + ((size_t)b * 256 + c) * RES_;
#pragma unroll
        for (int i0 = 0; i0 < 4; ++i0) {
            int p = tid + i0 * 256;
            int y = p >> 5, xx = p & 31;
            float aK = 0.f, aV = 0.f;
#pragma unroll
            for (int ky = 0; ky < 3; ++ky) {
                int yy = y + ky - 1;
                if ((unsigned)yy >= 32u) continue;
#pragma unroll
                for (int kx = 0; kx < 3; ++kx) {
                    int x2 = xx + kx - 1;
                    if ((unsigned)x2 >= 32u) continue;
                    float pv = plane[yy * 32 + x2];
                    aK = fmaf(wkr[ky * 3 + kx], pv, aK);
                    aV = fmaf(wvr[ky * 3 + kx], pv, aV);
                }
            }
            outK[p] = (__bf16)fmaf(aK, invK, shK);
            outV[p] = (__bf16)fmaf(aV, invV, shV);
        }
    } else {
        // ---- weight f32 -> bf16 ----
        int idx = blk - 1792;
        int m = idx >> 6;
        const float* s = m == 0 ? pw0 : m == 1 ? pw1 : m == 2 ? pw2 : pw3;
        __bf16*      d = m == 0 ? Wq  : m == 1 ? Wk  : m == 2 ? Wv  : Wo;
        int i = ((idx & 63) * 256 + tid) * 4;
        float4 v = *(const float4*)(s + i);
        ushort4 u;
        u.x = bfbits(v.x); u.y = bfbits(v.y); u.z = bfbits(v.z); u.w = bfbits(v.w);
        *(ushort4*)(d + i) = u;
    }
}

// ---------------------------------------------------------------------------
// K and V projection GEMMs. One 32x32 tile per wave.
// ---------------------------------------------------------------------------
__global__ __launch_bounds__(256) void gemm_kv_kernel(
    const __bf16* __restrict__ kt, const __bf16* __restrict__ vt,
    const __bf16* __restrict__ Wk, const __bf16* __restrict__ Wv,
    __bf16* __restrict__ Kb, __bf16* __restrict__ VT)
{
    int tid = threadIdx.x, lane = tid & 63, l31 = lane & 31, hi = lane >> 5;
    int gid = blockIdx.x * 4 + (tid >> 6);

    f32x16 acc;
#pragma unroll
    for (int r = 0; r < 16; ++r) acc[r] = 0.f;

    if (gid < 1024) {
        int g = gid;
        int b = g >> 8, rem = g & 255;
        int j0 = (rem >> 3) * 32, i0 = (rem & 7) * 32;
        const __bf16* Bbase = kt + (size_t)b * 256 * RES_ + j0 + l31;
        const __bf16* Ap = Wk + (size_t)(i0 + l31) * 256 + 8 * hi;
#pragma unroll
        for (int k0 = 0; k0 < 256; k0 += 16) {
            bf16x8 bfr;
#pragma unroll
            for (int jj = 0; jj < 8; ++jj)
                bfr[jj] = Bbase[(size_t)(k0 + 8 * hi + jj) * RES_];
            acc = __builtin_amdgcn_mfma_f32_32x32x16_bf16(
                *(const bf16x8*)(Ap + k0), bfr, acc, 0, 0, 0);
        }
        int head = i0 >> 5;
        __bf16* op = Kb + ((size_t)(b * HEADS_ + head) * RES_ + j0 + l31) * 32 + 4 * hi;
#pragma unroll
        for (int rr = 0; rr < 4; ++rr) {
            ushort4 u;
            u.x = bfbits(acc[4 * rr + 0]); u.y = bfbits(acc[4 * rr + 1]);
            u.z = bfbits(acc[4 * rr + 2]); u.w = bfbits(acc[4 * rr + 3]);
            *(ushort4*)(op + 8 * rr) = u;
        }
    } else {
        int g = gid - 1024;
        int b = g >> 8, rem = g & 255;
        int i0t = (rem >> 3) * 32, j0 = (rem & 7) * 32;
        const __bf16* Abase = vt + (size_t)b * 256 * RES_ + i0t + l31;
        const __bf16* Bp = Wv + (size_t)(j0 + l31) * 256 + 8 * hi;
#pragma unroll
        for (int k0 = 0; k0 < 256; k0 += 16) {
            bf16x8 afr;
#pragma unroll
            for (int jj = 0; jj < 8; ++jj)
                afr[jj] = Abase[(size_t)(k0 + 8 * hi + jj) * RES_];
            acc = __builtin_amdgcn_mfma_f32_32x32x16_bf16(
                afr, *(const bf16x8*)(Bp + k0), acc, 0, 0, 0);
        }
        int head = j0 >> 5;
        __bf16* op = VT + ((size_t)(b * HEADS_ + head) * 32 + l31) * RES_ + i0t + 4 * hi;
#pragma unroll
        for (int rr = 0; rr < 4; ++rr) {
            ushort4 u;
            u.x = bfbits(acc[4 * rr + 0]); u.y = bfbits(acc[4 * rr + 1]);
            u.z = bfbits(acc[4 * rr + 2]); u.w = bfbits(acc[4 * rr + 3]);
            *(ushort4*)(op + 8 * rr) = u;
        }
    }
}

// ---------------------------------------------------------------------------
// Final projection: D[n][l] = Wo . Oc^T + bias. One 32x32 tile per wave.
// ---------------------------------------------------------------------------
__global__ __launch_bounds__(256) void gemm_out_kernel(
    const __bf16* __restrict__ Oc, const __bf16* __restrict__ Wo,
    const float* __restrict__ bias, float* __restrict__ out)
{
    int tid = threadIdx.x, lane = tid & 63, l31 = lane & 31, hi = lane >> 5;
    int gid = blockIdx.x * 4 + (tid >> 6);
    int b = gid / 768, rem = gid % 768;
    int j0 = (rem >> 3) * 32, i0 = (rem & 7) * 32;
    const __bf16* Bp = Oc + ((size_t)b * LQ_ + j0 + l31) * 256 + 8 * hi;
    const __bf16* Ap = Wo + (size_t)(i0 + l31) * 256 + 8 * hi;

    f32x16 acc;
#pragma unroll
    for (int r = 0; r < 16; ++r) acc[r] = 0.f;
#pragma unroll
    for (int k0 = 0; k0 < 256; k0 += 16) {
        acc = __builtin_amdgcn_mfma_f32_32x32x16_bf16(
            *(const bf16x8*)(Ap + k0), *(const bf16x8*)(Bp + k0), acc, 0, 0, 0);
    }
    float* op = out + ((size_t)b * LQ_ + j0 + l31) * 256 + i0 + 4 * hi;
#pragma unroll
    for (int rr = 0; rr < 4; ++rr) {
        float4 bv = *(const float4*)(bias + i0 + 4 * hi + 8 * rr);
        float4 r4;
        r4.x = acc[4 * rr + 0] + bv.x; r4.y = acc[4 * rr + 1] + bv.y;
        r4.z = acc[4 * rr + 2] + bv.z; r4.w = acc[4 * rr + 3] + bv.w;
        *(float4*)(op + 8 * rr) = r4;
    }
}

// ---------------------------------------------------------------------------
// MFMA flash attention v9: v8 loop + LDS diet for residency.
//  - two-stage merge (quarters {2,3} publish; {0,1} absorb; {1} publishes;
//    {0} finalizes) => Os[2] instead of Os[3]
//  - Qlds overlaid on Os (consumed before first merge write; barrier-guarded)
//  - LDS 32.25 KB -> 17.9 KB; launch_bounds(256,5) => 5 blocks/CU
// ---------------------------------------------------------------------------
__global__ __launch_bounds__(256, 5) void attn_mfma_kernel(
    const __bf16* __restrict__ qt, const __bf16* __restrict__ Wq,
    const __bf16* __restrict__ Kb, const __bf16* __restrict__ VT,
    __bf16* __restrict__ Oc)
{
    __shared__ float Os[2][64][35];              // 17,920 B
    __bf16* Qlds = (__bf16*)&Os[0][0][0];        // overlay: [64 rows][40 cols]

    int tid  = threadIdx.x;
    int lane = tid & 63, l31 = lane & 31, hi = lane >> 5;
    int th   = tid >> 6;                    // t-quarter 0..3

    int i    = blockIdx.x;
    int xcd  = i & 7, slot = i >> 3;
    int bh   = xcd * 4 + slot / 48;
    int q0   = (slot % 48) * 64;
    int b    = bh >> 3, h = bh & 7;

    // ---- Q projection prologue (waves 0,1) ----
    if (th < 2) {
        const __bf16* Bp = qt + ((size_t)b * LQ_ + q0 + th * 32 + l31) * 256 + 8 * hi;
        const __bf16* Ap = Wq + (size_t)(h * 32 + l31) * 256 + 8 * hi;
        f32x16 acc;
#pragma unroll
        for (int r = 0; r < 16; ++r) acc[r] = 0.f;
#pragma unroll
        for (int k0 = 0; k0 < 256; k0 += 16) {
            acc = __builtin_amdgcn_mfma_f32_32x32x16_bf16(
                *(const bf16x8*)(Ap + k0), *(const bf16x8*)(Bp + k0), acc, 0, 0, 0);
        }
        const float scale = 0.0625f * 1.44269504f;   // 256^-0.5 * log2(e)
        __bf16* qp = Qlds + (size_t)(th * 32 + l31) * 40 + 4 * hi;
#pragma unroll
        for (int rr = 0; rr < 4; ++rr) {
            ushort4 u;
            u.x = bfbits(acc[4 * rr + 0] * scale); u.y = bfbits(acc[4 * rr + 1] * scale);
            u.z = bfbits(acc[4 * rr + 2] * scale); u.w = bfbits(acc[4 * rr + 3] * scale);
            *(ushort4*)(qp + 8 * rr) = u;
        }
    }
    __syncthreads();

    const __bf16* qbase = Qlds + (size_t)l31 * 40 + 8 * hi;
    bf16x8 qA0 = *(const bf16x8*)qbase;
    bf16x8 qA1 = *(const bf16x8*)(qbase + 16);
    bf16x8 qB0 = *(const bf16x8*)(qbase + 32 * 40);
    bf16x8 qB1 = *(const bf16x8*)(qbase + 32 * 40 + 16);
    __syncthreads();   // Qlds fully consumed; Os overlay now safe to write

    const __bf16* kp = Kb + ((size_t)bh * RES_ + th * 256 + l31) * 32 + 8 * hi;
    const __bf16* vp = VT + ((size_t)bh * 32 + l31) * RES_ + th * 256 + 8 * hi;

    f32x16 oA, oB;
#pragma unroll
    for (int r = 0; r < 16; ++r) { oA[r] = 0.f; oB[r] = 0.f; }
    float lsA = 0.f, lsB = 0.f;

    auto smpack = [&](const f32x16& s, float& ls, bf16x8& pb1, bf16x8& pb2) {
        float p[16];
#pragma unroll
        for (int r = 0; r < 16; ++r) p[r] = EXP2(s[r]);

        unsigned int w0 = pkbf(p[0],  p[1]),  w1 = pkbf(p[2],  p[3]);
        unsigned int w2 = pkbf(p[4],  p[5]),  w3 = pkbf(p[6],  p[7]);
        unsigned int w4 = pkbf(p[8],  p[9]),  w5 = pkbf(p[10], p[11]);
        unsigned int w6 = pkbf(p[12], p[13]), w7 = pkbf(p[14], p[15]);

        asm("v_permlane32_swap_b32 %0, %1" : "+v"(w0), "+v"(w2));
        asm("v_permlane32_swap_b32 %0, %1" : "+v"(w1), "+v"(w3));
        asm("v_permlane32_swap_b32 %0, %1" : "+v"(w4), "+v"(w6));
        asm("v_permlane32_swap_b32 %0, %1" : "+v"(w5), "+v"(w7));

        uint4e b1 = { w0, w1, w2, w3 };
        uint4e b2 = { w4, w5, w6, w7 };
        pb1 = __builtin_bit_cast(bf16x8, b1);
        pb2 = __builtin_bit_cast(bf16x8, b2);

        float t0 = (p[0]+p[1]) + (p[2]+p[3]);
        float t1 = (p[4]+p[5]) + (p[6]+p[7]);
        float t2 = (p[8]+p[9]) + (p[10]+p[11]);
        float t3 = (p[12]+p[13]) + (p[14]+p[15]);
        ls += (t0 + t1) + (t2 + t3);
    };

#pragma unroll
    for (int it = 0; it < 8; it += 2) {
        const __bf16* kA = kp + (size_t)it * 1024;
        const __bf16* kB = kp + (size_t)(it + 1) * 1024;
        const __bf16* vA = vp + (size_t)it * 32;
        const __bf16* vB = vp + (size_t)(it + 1) * 32;
        bf16x8 K00 = *(const bf16x8*)kA;
        bf16x8 K01 = *(const bf16x8*)(kA + 16);
        bf16x8 K10 = *(const bf16x8*)kB;
        bf16x8 K11 = *(const bf16x8*)(kB + 16);
        bf16x8 V00 = *(const bf16x8*)vA;
        bf16x8 V01 = *(const bf16x8*)(vA + 16);
        bf16x8 V10 = *(const bf16x8*)vB;
        bf16x8 V11 = *(const bf16x8*)(vB + 16);

        f32x16 sA0, sB0, sA1, sB1;
#pragma unroll
        for (int r = 0; r < 16; ++r) { sA0[r] = 0.f; sB0[r] = 0.f; sA1[r] = 0.f; sB1[r] = 0.f; }

        __builtin_amdgcn_s_setprio(1);
        sA0 = __builtin_amdgcn_mfma_f32_32x32x16_bf16(K00, qA0, sA0, 0, 0, 0);
        sB0 = __builtin_amdgcn_mfma_f32_32x32x16_bf16(K00, qB0, sB0, 0, 0, 0);
        sA1 = __builtin_amdgcn_mfma_f32_32x32x16_bf16(K10, qA0, sA1, 0, 0, 0);
        sB1 = __builtin_amdgcn_mfma_f32_32x32x16_bf16(K10, qB0, sB1, 0, 0, 0);
        sA0 = __builtin_amdgcn_mfma_f32_32x32x16_bf16(K01, qA1, sA0, 0, 0, 0);
        sB0 = __builtin_amdgcn_mfma_f32_32x32x16_bf16(K01, qB1, sB0, 0, 0, 0);
        sA1 = __builtin_amdgcn_mfma_f32_32x32x16_bf16(K11, qA1, sA1, 0, 0, 0);
        sB1 = __builtin_amdgcn_mfma_f32_32x32x16_bf16(K11, qB1, sB1, 0, 0, 0);
        __builtin_amdgcn_s_setprio(0);

        bf16x8 pA1, pA2, pB1, pB2;
        smpack(sA0, lsA, pA1, pA2);
        smpack(sB0, lsB, pB1, pB2);

        __builtin_amdgcn_s_setprio(1);
        oA = __builtin_amdgcn_mfma_f32_32x32x16_bf16(V00, pA1, oA, 0, 0, 0);
        oB = __builtin_amdgcn_mfma_f32_32x32x16_bf16(V00, pB1, oB, 0, 0, 0);
        oA = __builtin_amdgcn_mfma_f32_32x32x16_bf16(V01, pA2, oA, 0, 0, 0);
        oB = __builtin_amdgcn_mfma_f32_32x32x16_bf16(V01, pB2, oB, 0, 0, 0);
        __builtin_amdgcn_s_setprio(0);

        smpack(sA1, lsA, pA1, pA2);
        smpack(sB1, lsB, pB1, pB2);

        __builtin_amdgcn_s_setprio(1);
        oA = __builtin_amdgcn_mfma_f32_32x32x16_bf16(V10, pA1, oA, 0, 0, 0);
        oB = __builtin_amdgcn_mfma_f32_32x32x16_bf16(V10, pB1, oB, 0, 0, 0);
        oA = __builtin_amdgcn_mfma_f32_32x32x16_bf16(V11, pA2, oA, 0, 0, 0);
        oB = __builtin_amdgcn_mfma_f32_32x32x16_bf16(V11, pB2, oB, 0, 0, 0);
        __builtin_amdgcn_s_setprio(0);
    }

    lsA += __shfl_xor(lsA, 32, 64);
    lsB += __shfl_xor(lsB, 32, 64);

    // ---- two-stage merge: {2,3} publish -> {0,1} absorb -> {1} -> {0} ----
    if (th >= 2) {
        int s0 = th - 2;
#pragma unroll
        for (int r = 0; r < 16; ++r) {
            Os[s0][lane][r]      = oA[r];
            Os[s0][lane][17 + r] = oB[r];
        }
        Os[s0][lane][16] = lsA;
        Os[s0][lane][33] = lsB;
    }
    __syncthreads();
    if (th < 2) {
#pragma unroll
        for (int r = 0; r < 16; ++r) {
            oA[r] += Os[th][lane][r];
            oB[r] += Os[th][lane][17 + r];
        }
        lsA += Os[th][lane][16];
        lsB += Os[th][lane][33];
    }
    __syncthreads();
    if (th == 1) {
#pragma unroll
        for (int r = 0; r < 16; ++r) {
            Os[0][lane][r]      = oA[r];
            Os[0][lane][17 + r] = oB[r];
        }
        Os[0][lane][16] = lsA;
        Os[0][lane][33] = lsB;
    }
    __syncthreads();
    if (th == 0) {
        float lA = lsA + Os[0][lane][16];
        float lB = lsB + Os[0][lane][33];
        float invA = 1.0f / lA, invB = 1.0f / lB;
        __bf16* opA = Oc + ((size_t)b * LQ_ + q0 + l31) * 256 + h * 32 + 4 * hi;
        __bf16* opB = opA + (size_t)32 * 256;
#pragma unroll
        for (int rr = 0; rr < 4; ++rr) {
            ushort4 ua, ub;
            ua.x = bfbits((oA[4*rr+0] + Os[0][lane][4*rr+0]) * invA);
            ua.y = bfbits((oA[4*rr+1] + Os[0][lane][4*rr+1]) * invA);
            ua.z = bfbits((oA[4*rr+2] + Os[0][lane][4*rr+2]) * invA);
            ua.w = bfbits((oA[4*rr+3] + Os[0][lane][4*rr+3]) * invA);
            ub.x = bfbits((oB[4*rr+0] + Os[0][lane][17+4*rr+0]) * invB);
            ub.y = bfbits((oB[4*rr+1] + Os[0][lane][17+4*rr+1]) * invB);
            ub.z = bfbits((oB[4*rr+2] + Os[0][lane][17+4*rr+2]) * invB);
            ub.w = bfbits((oB[4*rr+3] + Os[0][lane][17+4*rr+3]) * invB);
            *(ushort4*)(opA + 8 * rr) = ua;
            *(ushort4*)(opB + 8 * rr) = ub;
        }
    }
}

// ---------------------------------------------------------------------------
extern "C" void kernel_launch(void* const* d_in, const int* in_sizes, int n_in,
                              void* d_out, int out_size, void* d_ws, size_t ws_size,
                              hipStream_t stream) {
    const float* x        = (const float*)d_in[0];
    const float* query    = (const float*)d_in[1];
    const float* conv_q_w = (const float*)d_in[2];
    const float* bn_q_g   = (const float*)d_in[3];
    const float* bn_q_b   = (const float*)d_in[4];
    const float* bn_q_m   = (const float*)d_in[5];
    const float* bn_q_v   = (const float*)d_in[6];
    const float* conv_k_w = (const float*)d_in[7];
    const float* bn_k_g   = (const float*)d_in[8];
    const float* bn_k_b   = (const float*)d_in[9];
    const float* bn_k_m   = (const float*)d_in[10];
    const float* bn_k_v   = (const float*)d_in[11];
    const float* conv_v_w = (const float*)d_in[12];
    const float* bn_v_g   = (const float*)d_in[13];
    const float* bn_v_b   = (const float*)d_in[14];
    const float* bn_v_m   = (const float*)d_in[15];
    const float* bn_v_v   = (const float*)d_in[16];
    const float* proj_q_w = (const float*)d_in[17];
    const float* proj_k_w = (const float*)d_in[18];
    const float* proj_v_w = (const float*)d_in[19];
    const float* proj_w   = (const float*)d_in[20];
    const float* proj_b   = (const float*)d_in[21];

    char* ws = (char*)d_ws;
    __bf16* q_tok = (__bf16*)(ws + 0);          //  6,291,456 B
    __bf16* k_tok = (__bf16*)(ws + 6291456);    //  2,097,152 B
    __bf16* v_tok = (__bf16*)(ws + 8388608);    //  2,097,152 B
    __bf16* Kb    = (__bf16*)(ws + 10485760);   //  2,097,152 B
    __bf16* VT    = (__bf16*)(ws + 12582912);   //  2,097,152 B
    __bf16* Wq    = (__bf16*)(ws + 14680064);   //    131,072 B each
    __bf16* Wk    = (__bf16*)(ws + 14811136);
    __bf16* Wv    = (__bf16*)(ws + 14942208);
    __bf16* Wo    = (__bf16*)(ws + 15073280);
    __bf16* Oc    = (__bf16*)(ws + 15204352);   //  6,291,456 B
    float*  out   = (float*)d_out;

    pre_kernel<<<dim3(2048), 256, 0, stream>>>(
        query, x, conv_q_w, bn_q_g, bn_q_b, bn_q_m, bn_q_v,
        conv_k_w, bn_k_g, bn_k_b, bn_k_m, bn_k_v,
        conv_v_w, bn_v_g, bn_v_b, bn_v_m, bn_v_v,
        proj_q_w, proj_k_w, proj_v_w, proj_w,
        q_tok, k_tok, v_tok, Wq, Wk, Wv, Wo);

    gemm_kv_kernel<<<dim3(512), 256, 0, stream>>>(
        k_tok, v_tok, Wk, Wv, Kb, VT);

    attn_mfma_kernel<<<dim3(1536), 256, 0, stream>>>(q_tok, Wq, Kb, VT, Oc);

    gemm_out_kernel<<<dim3(768), 256, 0, stream>>>(Oc, Wo, proj_b, out);
}

// Round 14
// 92.553 us; speedup vs baseline: 2.1373x; 2.1373x over previous
//
#include <hip/hip_runtime.h>
#include <hip/hip_bf16.h>
#include <math.h>

#define B_     4
#define C_     256
#define RES_   1024
#define FEA_   3
#define LQ_    3072
#define HEADS_ 8
#define EPS_   1e-5f

typedef __bf16 bf16x8 __attribute__((ext_vector_type(8)));
typedef float  f32x16 __attribute__((ext_vector_type(16)));
typedef unsigned int uint4e __attribute__((ext_vector_type(4)));

#if __has_builtin(__builtin_amdgcn_exp2f)
#define EXP2(x) __builtin_amdgcn_exp2f(x)
#else
#define EXP2(x) exp2f(x)
#endif

__device__ __forceinline__ unsigned short bfbits(float v) {
    return __builtin_bit_cast(unsigned short, (__bf16)v);
}
__device__ __forceinline__ unsigned int pkbf(float lo, float hi2) {
    return (unsigned int)bfbits(lo) | ((unsigned int)bfbits(hi2) << 16);
}

// ---------------------------------------------------------------------------
// Fused pre-pass:
//   conv_q 4x4-token tiles   [0, 768)
//   conv_kv (K+V fused, one x-plane load, bf16 out)  [768, 1792)
//   weight cvt               [1792, 2048)
// ---------------------------------------------------------------------------
__global__ __launch_bounds__(256) void pre_kernel(
    const float* __restrict__ query, const float* __restrict__ x,
    const float* __restrict__ wq,
    const float* __restrict__ gq, const float* __restrict__ bq,
    const float* __restrict__ mq, const float* __restrict__ vq,
    const float* __restrict__ wk, const float* __restrict__ gk, const float* __restrict__ bk,
    const float* __restrict__ mk, const float* __restrict__ vk,
    const float* __restrict__ wv, const float* __restrict__ gv, const float* __restrict__ bv,
    const float* __restrict__ mv, const float* __restrict__ vv,
    const float* __restrict__ pw0, const float* __restrict__ pw1,
    const float* __restrict__ pw2, const float* __restrict__ pw3,
    __bf16* __restrict__ q_tok, __bf16* __restrict__ k_tok, __bf16* __restrict__ v_tok,
    __bf16* __restrict__ Wq, __bf16* __restrict__ Wk,
    __bf16* __restrict__ Wv, __bf16* __restrict__ Wo)
{
    __shared__ float plane[RES_];
    int blk = blockIdx.x, tid = threadIdx.x;

    if (blk < 768) {
        // ---- conv_q: one block per (b, part, 4x4 tile); thread = channel ----
        int b = blk / 192, rem = blk % 192;
        int part = rem >> 6, t = rem & 63;
        int y0 = (t >> 3) * 4, x0 = (t & 7) * 4;
        int c = tid;
        const float* wp = wq + (size_t)(part * 256 + c) * 9;
        const float* qb = query + ((size_t)b * LQ_ + (size_t)part * 1024) * 256 + c;

        float w[9];
#pragma unroll
        for (int i = 0; i < 9; ++i) w[i] = wp[i];

        float v[6][6];
#pragma unroll
        for (int iy = 0; iy < 6; ++iy) {
            int yy = y0 - 1 + iy;
#pragma unroll
            for (int ix = 0; ix < 6; ++ix) {
                int xx = x0 - 1 + ix;
                bool ok = ((unsigned)yy < 32u) && ((unsigned)xx < 32u);
                v[iy][ix] = ok ? qb[(size_t)(yy * 32 + xx) * 256] : 0.f;
            }
        }
        int gi = part * 256 + c;
        float inv = gq[gi] * rsqrtf(vq[gi] + EPS_);
        float sh  = bq[gi] - mq[gi] * inv;
#pragma unroll
        for (int yi = 0; yi < 4; ++yi) {
#pragma unroll
            for (int xi = 0; xi < 4; ++xi) {
                float acc = 0.f;
#pragma unroll
                for (int ky = 0; ky < 3; ++ky)
#pragma unroll
                    for (int kj = 0; kj < 3; ++kj)
                        acc = fmaf(w[ky * 3 + kj], v[yi + ky][xi + kj], acc);
                int l = part * 1024 + (y0 + yi) * 32 + x0 + xi;
                q_tok[((size_t)b * LQ_ + l) * 256 + c] = (__bf16)fmaf(acc, inv, sh);
            }
        }
    } else if (blk < 1792) {
        // ---- conv_kv: one block per (c, b); computes BOTH K and V convs ----
        int idx = blk - 768;
        int c = idx & 255, b = idx >> 8;
        const float* xp = x + ((size_t)b * 256 + c) * RES_;
#pragma unroll
        for (int i = 0; i < 4; ++i) plane[tid + i * 256] = xp[tid + i * 256];
        __syncthreads();

        const float* wpk = wk + (size_t)c * 9;
        const float* wpv = wv + (size_t)c * 9;
        float wkr[9], wvr[9];
#pragma unroll
        for (int i = 0; i < 9; ++i) { wkr[i] = wpk[i]; wvr[i] = wpv[i]; }
        float invK = gk[c] * rsqrtf(vk[c] + EPS_);
        float shK  = bk[c] - mk[c] * invK;
        float invV = gv[c] * rsqrtf(vv[c] + EPS_);
        float shV  = bv[c] - mv[c] * invV;
        __bf16* outK = k_tok + ((size_t)b * 256 + c) * RES_;
        __bf16* outV = v_tok + ((size_t)b * 256 + c) * RES_;
#pragma unroll
        for (int i0 = 0; i0 < 4; ++i0) {
            int p = tid + i0 * 256;
            int y = p >> 5, xx = p & 31;
            float aK = 0.f, aV = 0.f;
#pragma unroll
            for (int ky = 0; ky < 3; ++ky) {
                int yy = y + ky - 1;
                if ((unsigned)yy >= 32u) continue;
#pragma unroll
                for (int kx = 0; kx < 3; ++kx) {
                    int x2 = xx + kx - 1;
                    if ((unsigned)x2 >= 32u) continue;
                    float pv = plane[yy * 32 + x2];
                    aK = fmaf(wkr[ky * 3 + kx], pv, aK);
                    aV = fmaf(wvr[ky * 3 + kx], pv, aV);
                }
            }
            outK[p] = (__bf16)fmaf(aK, invK, shK);
            outV[p] = (__bf16)fmaf(aV, invV, shV);
        }
    } else {
        // ---- weight f32 -> bf16 ----
        int idx = blk - 1792;
        int m = idx >> 6;
        const float* s = m == 0 ? pw0 : m == 1 ? pw1 : m == 2 ? pw2 : pw3;
        __bf16*      d = m == 0 ? Wq  : m == 1 ? Wk  : m == 2 ? Wv  : Wo;
        int i = ((idx & 63) * 256 + tid) * 4;
        float4 v = *(const float4*)(s + i);
        ushort4 u;
        u.x = bfbits(v.x); u.y = bfbits(v.y); u.z = bfbits(v.z); u.w = bfbits(v.w);
        *(ushort4*)(d + i) = u;
    }
}

// ---------------------------------------------------------------------------
// K and V projection GEMMs. One 32x32 tile per wave.
// ---------------------------------------------------------------------------
__global__ __launch_bounds__(256) void gemm_kv_kernel(
    const __bf16* __restrict__ kt, const __bf16* __restrict__ vt,
    const __bf16* __restrict__ Wk, const __bf16* __restrict__ Wv,
    __bf16* __restrict__ Kb, __bf16* __restrict__ VT)
{
    int tid = threadIdx.x, lane = tid & 63, l31 = lane & 31, hi = lane >> 5;
    int gid = blockIdx.x * 4 + (tid >> 6);

    f32x16 acc;
#pragma unroll
    for (int r = 0; r < 16; ++r) acc[r] = 0.f;

    if (gid < 1024) {
        int g = gid;
        int b = g >> 8, rem = g & 255;
        int j0 = (rem >> 3) * 32, i0 = (rem & 7) * 32;
        const __bf16* Bbase = kt + (size_t)b * 256 * RES_ + j0 + l31;
        const __bf16* Ap = Wk + (size_t)(i0 + l31) * 256 + 8 * hi;
#pragma unroll
        for (int k0 = 0; k0 < 256; k0 += 16) {
            bf16x8 bfr;
#pragma unroll
            for (int jj = 0; jj < 8; ++jj)
                bfr[jj] = Bbase[(size_t)(k0 + 8 * hi + jj) * RES_];
            acc = __builtin_amdgcn_mfma_f32_32x32x16_bf16(
                *(const bf16x8*)(Ap + k0), bfr, acc, 0, 0, 0);
        }
        int head = i0 >> 5;
        __bf16* op = Kb + ((size_t)(b * HEADS_ + head) * RES_ + j0 + l31) * 32 + 4 * hi;
#pragma unroll
        for (int rr = 0; rr < 4; ++rr) {
            ushort4 u;
            u.x = bfbits(acc[4 * rr + 0]); u.y = bfbits(acc[4 * rr + 1]);
            u.z = bfbits(acc[4 * rr + 2]); u.w = bfbits(acc[4 * rr + 3]);
            *(ushort4*)(op + 8 * rr) = u;
        }
    } else {
        int g = gid - 1024;
        int b = g >> 8, rem = g & 255;
        int i0t = (rem >> 3) * 32, j0 = (rem & 7) * 32;
        const __bf16* Abase = vt + (size_t)b * 256 * RES_ + i0t + l31;
        const __bf16* Bp = Wv + (size_t)(j0 + l31) * 256 + 8 * hi;
#pragma unroll
        for (int k0 = 0; k0 < 256; k0 += 16) {
            bf16x8 afr;
#pragma unroll
            for (int jj = 0; jj < 8; ++jj)
                afr[jj] = Abase[(size_t)(k0 + 8 * hi + jj) * RES_];
            acc = __builtin_amdgcn_mfma_f32_32x32x16_bf16(
                afr, *(const bf16x8*)(Bp + k0), acc, 0, 0, 0);
        }
        int head = j0 >> 5;
        __bf16* op = VT + ((size_t)(b * HEADS_ + head) * 32 + l31) * RES_ + i0t + 4 * hi;
#pragma unroll
        for (int rr = 0; rr < 4; ++rr) {
            ushort4 u;
            u.x = bfbits(acc[4 * rr + 0]); u.y = bfbits(acc[4 * rr + 1]);
            u.z = bfbits(acc[4 * rr + 2]); u.w = bfbits(acc[4 * rr + 3]);
            *(ushort4*)(op + 8 * rr) = u;
        }
    }
}

// ---------------------------------------------------------------------------
// Final projection: D[n][l] = Wo . Oc^T + bias. One 32x32 tile per wave.
// ---------------------------------------------------------------------------
__global__ __launch_bounds__(256) void gemm_out_kernel(
    const __bf16* __restrict__ Oc, const __bf16* __restrict__ Wo,
    const float* __restrict__ bias, float* __restrict__ out)
{
    int tid = threadIdx.x, lane = tid & 63, l31 = lane & 31, hi = lane >> 5;
    int gid = blockIdx.x * 4 + (tid >> 6);
    int b = gid / 768, rem = gid % 768;
    int j0 = (rem >> 3) * 32, i0 = (rem & 7) * 32;
    const __bf16* Bp = Oc + ((size_t)b * LQ_ + j0 + l31) * 256 + 8 * hi;
    const __bf16* Ap = Wo + (size_t)(i0 + l31) * 256 + 8 * hi;

    f32x16 acc;
#pragma unroll
    for (int r = 0; r < 16; ++r) acc[r] = 0.f;
#pragma unroll
    for (int k0 = 0; k0 < 256; k0 += 16) {
        acc = __builtin_amdgcn_mfma_f32_32x32x16_bf16(
            *(const bf16x8*)(Ap + k0), *(const bf16x8*)(Bp + k0), acc, 0, 0, 0);
    }
    float* op = out + ((size_t)b * LQ_ + j0 + l31) * 256 + i0 + 4 * hi;
#pragma unroll
    for (int rr = 0; rr < 4; ++rr) {
        float4 bv = *(const float4*)(bias + i0 + 4 * hi + 8 * rr);
        float4 r4;
        r4.x = acc[4 * rr + 0] + bv.x; r4.y = acc[4 * rr + 1] + bv.y;
        r4.z = acc[4 * rr + 2] + bv.z; r4.w = acc[4 * rr + 3] + bv.w;
        *(float4*)(op + 8 * rr) = r4;
    }
}

// ---------------------------------------------------------------------------
// MFMA flash attention v10: R12's proven v8 loop + one-stage merge (Os[3])
// with Qlds OVERLAID on Os (LDS 32,256 -> 26,880 B => 6 blocks/CU co-resident
// with the full 1536-block grid). launch_bounds(256,4): VGPR cap 128 >> 76,
// no spill (R13's (256,5) spill lesson).
// ---------------------------------------------------------------------------
__global__ __launch_bounds__(256, 4) void attn_mfma_kernel(
    const __bf16* __restrict__ qt, const __bf16* __restrict__ Wq,
    const __bf16* __restrict__ Kb, const __bf16* __restrict__ VT,
    __bf16* __restrict__ Oc)
{
    __shared__ float Os[3][64][35];              // 26,880 B
    __bf16* Qlds = (__bf16*)&Os[0][0][0];        // overlay: [64 rows][40 cols]

    int tid  = threadIdx.x;
    int lane = tid & 63, l31 = lane & 31, hi = lane >> 5;
    int th   = tid >> 6;                    // t-quarter 0..3

    int i    = blockIdx.x;
    int xcd  = i & 7, slot = i >> 3;
    int bh   = xcd * 4 + slot / 48;
    int q0   = (slot % 48) * 64;
    int b    = bh >> 3, h = bh & 7;

    // ---- Q projection prologue (waves 0,1) ----
    if (th < 2) {
        const __bf16* Bp = qt + ((size_t)b * LQ_ + q0 + th * 32 + l31) * 256 + 8 * hi;
        const __bf16* Ap = Wq + (size_t)(h * 32 + l31) * 256 + 8 * hi;
        f32x16 acc;
#pragma unroll
        for (int r = 0; r < 16; ++r) acc[r] = 0.f;
#pragma unroll
        for (int k0 = 0; k0 < 256; k0 += 16) {
            acc = __builtin_amdgcn_mfma_f32_32x32x16_bf16(
                *(const bf16x8*)(Ap + k0), *(const bf16x8*)(Bp + k0), acc, 0, 0, 0);
        }
        const float scale = 0.0625f * 1.44269504f;   // 256^-0.5 * log2(e)
        __bf16* qp = Qlds + (size_t)(th * 32 + l31) * 40 + 4 * hi;
#pragma unroll
        for (int rr = 0; rr < 4; ++rr) {
            ushort4 u;
            u.x = bfbits(acc[4 * rr + 0] * scale); u.y = bfbits(acc[4 * rr + 1] * scale);
            u.z = bfbits(acc[4 * rr + 2] * scale); u.w = bfbits(acc[4 * rr + 3] * scale);
            *(ushort4*)(qp + 8 * rr) = u;
        }
    }
    __syncthreads();

    const __bf16* qbase = Qlds + (size_t)l31 * 40 + 8 * hi;
    bf16x8 qA0 = *(const bf16x8*)qbase;
    bf16x8 qA1 = *(const bf16x8*)(qbase + 16);
    bf16x8 qB0 = *(const bf16x8*)(qbase + 32 * 40);
    bf16x8 qB1 = *(const bf16x8*)(qbase + 32 * 40 + 16);
    __syncthreads();   // Qlds fully consumed; Os overlay now safe to write

    const __bf16* kp = Kb + ((size_t)bh * RES_ + th * 256 + l31) * 32 + 8 * hi;
    const __bf16* vp = VT + ((size_t)bh * 32 + l31) * RES_ + th * 256 + 8 * hi;

    f32x16 oA, oB;
#pragma unroll
    for (int r = 0; r < 16; ++r) { oA[r] = 0.f; oB[r] = 0.f; }
    float lsA = 0.f, lsB = 0.f;

    auto smpack = [&](const f32x16& s, float& ls, bf16x8& pb1, bf16x8& pb2) {
        float p[16];
#pragma unroll
        for (int r = 0; r < 16; ++r) p[r] = EXP2(s[r]);

        unsigned int w0 = pkbf(p[0],  p[1]),  w1 = pkbf(p[2],  p[3]);
        unsigned int w2 = pkbf(p[4],  p[5]),  w3 = pkbf(p[6],  p[7]);
        unsigned int w4 = pkbf(p[8],  p[9]),  w5 = pkbf(p[10], p[11]);
        unsigned int w6 = pkbf(p[12], p[13]), w7 = pkbf(p[14], p[15]);

        asm("v_permlane32_swap_b32 %0, %1" : "+v"(w0), "+v"(w2));
        asm("v_permlane32_swap_b32 %0, %1" : "+v"(w1), "+v"(w3));
        asm("v_permlane32_swap_b32 %0, %1" : "+v"(w4), "+v"(w6));
        asm("v_permlane32_swap_b32 %0, %1" : "+v"(w5), "+v"(w7));

        uint4e b1 = { w0, w1, w2, w3 };
        uint4e b2 = { w4, w5, w6, w7 };
        pb1 = __builtin_bit_cast(bf16x8, b1);
        pb2 = __builtin_bit_cast(bf16x8, b2);

        float t0 = (p[0]+p[1]) + (p[2]+p[3]);
        float t1 = (p[4]+p[5]) + (p[6]+p[7]);
        float t2 = (p[8]+p[9]) + (p[10]+p[11]);
        float t3 = (p[12]+p[13]) + (p[14]+p[15]);
        ls += (t0 + t1) + (t2 + t3);
    };

#pragma unroll
    for (int it = 0; it < 8; it += 2) {
        const __bf16* kA = kp + (size_t)it * 1024;
        const __bf16* kB = kp + (size_t)(it + 1) * 1024;
        const __bf16* vA = vp + (size_t)it * 32;
        const __bf16* vB = vp + (size_t)(it + 1) * 32;
        bf16x8 K00 = *(const bf16x8*)kA;
        bf16x8 K01 = *(const bf16x8*)(kA + 16);
        bf16x8 K10 = *(const bf16x8*)kB;
        bf16x8 K11 = *(const bf16x8*)(kB + 16);
        bf16x8 V00 = *(const bf16x8*)vA;
        bf16x8 V01 = *(const bf16x8*)(vA + 16);
        bf16x8 V10 = *(const bf16x8*)vB;
        bf16x8 V11 = *(const bf16x8*)(vB + 16);

        f32x16 sA0, sB0, sA1, sB1;
#pragma unroll
        for (int r = 0; r < 16; ++r) { sA0[r] = 0.f; sB0[r] = 0.f; sA1[r] = 0.f; sB1[r] = 0.f; }

        __builtin_amdgcn_s_setprio(1);
        sA0 = __builtin_amdgcn_mfma_f32_32x32x16_bf16(K00, qA0, sA0, 0, 0, 0);
        sB0 = __builtin_amdgcn_mfma_f32_32x32x16_bf16(K00, qB0, sB0, 0, 0, 0);
        sA1 = __builtin_amdgcn_mfma_f32_32x32x16_bf16(K10, qA0, sA1, 0, 0, 0);
        sB1 = __builtin_amdgcn_mfma_f32_32x32x16_bf16(K10, qB0, sB1, 0, 0, 0);
        sA0 = __builtin_amdgcn_mfma_f32_32x32x16_bf16(K01, qA1, sA0, 0, 0, 0);
        sB0 = __builtin_amdgcn_mfma_f32_32x32x16_bf16(K01, qB1, sB0, 0, 0, 0);
        sA1 = __builtin_amdgcn_mfma_f32_32x32x16_bf16(K11, qA1, sA1, 0, 0, 0);
        sB1 = __builtin_amdgcn_mfma_f32_32x32x16_bf16(K11, qB1, sB1, 0, 0, 0);
        __builtin_amdgcn_s_setprio(0);

        bf16x8 pA1, pA2, pB1, pB2;
        smpack(sA0, lsA, pA1, pA2);
        smpack(sB0, lsB, pB1, pB2);

        __builtin_amdgcn_s_setprio(1);
        oA = __builtin_amdgcn_mfma_f32_32x32x16_bf16(V00, pA1, oA, 0, 0, 0);
        oB = __builtin_amdgcn_mfma_f32_32x32x16_bf16(V00, pB1, oB, 0, 0, 0);
        oA = __builtin_amdgcn_mfma_f32_32x32x16_bf16(V01, pA2, oA, 0, 0, 0);
        oB = __builtin_amdgcn_mfma_f32_32x32x16_bf16(V01, pB2, oB, 0, 0, 0);
        __builtin_amdgcn_s_setprio(0);

        smpack(sA1, lsA, pA1, pA2);
        smpack(sB1, lsB, pB1, pB2);

        __builtin_amdgcn_s_setprio(1);
        oA = __builtin_amdgcn_mfma_f32_32x32x16_bf16(V10, pA1, oA, 0, 0, 0);
        oB = __builtin_amdgcn_mfma_f32_32x32x16_bf16(V10, pB1, oB, 0, 0, 0);
        oA = __builtin_amdgcn_mfma_f32_32x32x16_bf16(V11, pA2, oA, 0, 0, 0);
        oB = __builtin_amdgcn_mfma_f32_32x32x16_bf16(V11, pB2, oB, 0, 0, 0);
        __builtin_amdgcn_s_setprio(0);
    }

    lsA += __shfl_xor(lsA, 32, 64);
    lsB += __shfl_xor(lsB, 32, 64);

    // ---- one-stage merge (R12 verbatim): th>=1 publish, th==0 combines ----
    if (th) {
#pragma unroll
        for (int r = 0; r < 16; ++r) {
            Os[th - 1][lane][r]      = oA[r];
            Os[th - 1][lane][17 + r] = oB[r];
        }
        Os[th - 1][lane][16] = lsA;
        Os[th - 1][lane][33] = lsB;
    }
    __syncthreads();
    if (!th) {
        float lA = lsA + Os[0][lane][16] + Os[1][lane][16] + Os[2][lane][16];
        float lB = lsB + Os[0][lane][33] + Os[1][lane][33] + Os[2][lane][33];
        float invA = 1.0f / lA, invB = 1.0f / lB;
        __bf16* opA = Oc + ((size_t)b * LQ_ + q0 + l31) * 256 + h * 32 + 4 * hi;
        __bf16* opB = opA + (size_t)32 * 256;
#pragma unroll
        for (int rr = 0; rr < 4; ++rr) {
            ushort4 ua, ub;
            ua.x = bfbits((oA[4*rr+0] + Os[0][lane][4*rr+0] + Os[1][lane][4*rr+0] + Os[2][lane][4*rr+0]) * invA);
            ua.y = bfbits((oA[4*rr+1] + Os[0][lane][4*rr+1] + Os[1][lane][4*rr+1] + Os[2][lane][4*rr+1]) * invA);
            ua.z = bfbits((oA[4*rr+2] + Os[0][lane][4*rr+2] + Os[1][lane][4*rr+2] + Os[2][lane][4*rr+2]) * invA);
            ua.w = bfbits((oA[4*rr+3] + Os[0][lane][4*rr+3] + Os[1][lane][4*rr+3] + Os[2][lane][4*rr+3]) * invA);
            ub.x = bfbits((oB[4*rr+0] + Os[0][lane][17+4*rr+0] + Os[1][lane][17+4*rr+0] + Os[2][lane][17+4*rr+0]) * invB);
            ub.y = bfbits((oB[4*rr+1] + Os[0][lane][17+4*rr+1] + Os[1][lane][17+4*rr+1] + Os[2][lane][17+4*rr+1]) * invB);
            ub.z = bfbits((oB[4*rr+2] + Os[0][lane][17+4*rr+2] + Os[1][lane][17+4*rr+2] + Os[2][lane][17+4*rr+2]) * invB);
            ub.w = bfbits((oB[4*rr+3] + Os[0][lane][17+4*rr+3] + Os[1][lane][17+4*rr+3] + Os[2][lane][17+4*rr+3]) * invB);
            *(ushort4*)(opA + 8 * rr) = ua;
            *(ushort4*)(opB + 8 * rr) = ub;
        }
    }
}

// ---------------------------------------------------------------------------
extern "C" void kernel_launch(void* const* d_in, const int* in_sizes, int n_in,
                              void* d_out, int out_size, void* d_ws, size_t ws_size,
                              hipStream_t stream) {
    const float* x        = (const float*)d_in[0];
    const float* query    = (const float*)d_in[1];
    const float* conv_q_w = (const float*)d_in[2];
    const float* bn_q_g   = (const float*)d_in[3];
    const float* bn_q_b   = (const float*)d_in[4];
    const float* bn_q_m   = (const float*)d_in[5];
    const float* bn_q_v   = (const float*)d_in[6];
    const float* conv_k_w = (const float*)d_in[7];
    const float* bn_k_g   = (const float*)d_in[8];
    const float* bn_k_b   = (const float*)d_in[9];
    const float* bn_k_m   = (const float*)d_in[10];
    const float* bn_k_v   = (const float*)d_in[11];
    const float* conv_v_w = (const float*)d_in[12];
    const float* bn_v_g   = (const float*)d_in[13];
    const float* bn_v_b   = (const float*)d_in[14];
    const float* bn_v_m   = (const float*)d_in[15];
    const float* bn_v_v   = (const float*)d_in[16];
    const float* proj_q_w = (const float*)d_in[17];
    const float* proj_k_w = (const float*)d_in[18];
    const float* proj_v_w = (const float*)d_in[19];
    const float* proj_w   = (const float*)d_in[20];
    const float* proj_b   = (const float*)d_in[21];

    char* ws = (char*)d_ws;
    __bf16* q_tok = (__bf16*)(ws + 0);          //  6,291,456 B
    __bf16* k_tok = (__bf16*)(ws + 6291456);    //  2,097,152 B
    __bf16* v_tok = (__bf16*)(ws + 8388608);    //  2,097,152 B
    __bf16* Kb    = (__bf16*)(ws + 10485760);   //  2,097,152 B
    __bf16* VT    = (__bf16*)(ws + 12582912);   //  2,097,152 B
    __bf16* Wq    = (__bf16*)(ws + 14680064);   //    131,072 B each
    __bf16* Wk    = (__bf16*)(ws + 14811136);
    __bf16* Wv    = (__bf16*)(ws + 14942208);
    __bf16* Wo    = (__bf16*)(ws + 15073280);
    __bf16* Oc    = (__bf16*)(ws + 15204352);   //  6,291,456 B
    float*  out   = (float*)d_out;

    pre_kernel<<<dim3(2048), 256, 0, stream>>>(
        query, x, conv_q_w, bn_q_g, bn_q_b, bn_q_m, bn_q_v,
        conv_k_w, bn_k_g, bn_k_b, bn_k_m, bn_k_v,
        conv_v_w, bn_v_g, bn_v_b, bn_v_m, bn_v_v,
        proj_q_w, proj_k_w, proj_v_w, proj_w,
        q_tok, k_tok, v_tok, Wq, Wk, Wv, Wo);

    gemm_kv_kernel<<<dim3(512), 256, 0, stream>>>(
        k_tok, v_tok, Wk, Wv, Kb, VT);

    attn_mfma_kernel<<<dim3(1536), 256, 0, stream>>>(q_tok, Wq, Kb, VT, Oc);

    gemm_out_kernel<<<dim3(768), 256, 0, stream>>>(Oc, Wo, proj_b, out);
}

// Round 15
// 70.865 us; speedup vs baseline: 2.7914x; 1.3060x over previous
//
#include <hip/hip_runtime.h>
#include <hip/hip_bf16.h>
#include <math.h>

#define B_     4
#define C_     256
#define RES_   1024
#define FEA_   3
#define LQ_    3072
#define HEADS_ 8
#define EPS_   1e-5f

typedef __bf16 bf16x8 __attribute__((ext_vector_type(8)));
typedef float  f32x16 __attribute__((ext_vector_type(16)));
typedef unsigned int uint4e __attribute__((ext_vector_type(4)));

#if __has_builtin(__builtin_amdgcn_exp2f)
#define EXP2(x) __builtin_amdgcn_exp2f(x)
#else
#define EXP2(x) exp2f(x)
#endif

__device__ __forceinline__ unsigned short bfbits(float v) {
    return __builtin_bit_cast(unsigned short, (__bf16)v);
}
__device__ __forceinline__ unsigned int pkbf(float lo, float hi2) {
    return (unsigned int)bfbits(lo) | ((unsigned int)bfbits(hi2) << 16);
}

// ---------------------------------------------------------------------------
// Fused pre-pass:
//   conv_q 4x4-token tiles   [0, 768)
//   conv_kv (K+V fused, one x-plane load, bf16 out)  [768, 1792)
//   weight cvt               [1792, 2048)
// ---------------------------------------------------------------------------
__global__ __launch_bounds__(256) void pre_kernel(
    const float* __restrict__ query, const float* __restrict__ x,
    const float* __restrict__ wq,
    const float* __restrict__ gq, const float* __restrict__ bq,
    const float* __restrict__ mq, const float* __restrict__ vq,
    const float* __restrict__ wk, const float* __restrict__ gk, const float* __restrict__ bk,
    const float* __restrict__ mk, const float* __restrict__ vk,
    const float* __restrict__ wv, const float* __restrict__ gv, const float* __restrict__ bv,
    const float* __restrict__ mv, const float* __restrict__ vv,
    const float* __restrict__ pw0, const float* __restrict__ pw1,
    const float* __restrict__ pw2, const float* __restrict__ pw3,
    __bf16* __restrict__ q_tok, __bf16* __restrict__ k_tok, __bf16* __restrict__ v_tok,
    __bf16* __restrict__ Wq, __bf16* __restrict__ Wk,
    __bf16* __restrict__ Wv, __bf16* __restrict__ Wo)
{
    __shared__ float plane[RES_];
    int blk = blockIdx.x, tid = threadIdx.x;

    if (blk < 768) {
        // ---- conv_q: one block per (b, part, 4x4 tile); thread = channel ----
        int b = blk / 192, rem = blk % 192;
        int part = rem >> 6, t = rem & 63;
        int y0 = (t >> 3) * 4, x0 = (t & 7) * 4;
        int c = tid;
        const float* wp = wq + (size_t)(part * 256 + c) * 9;
        const float* qb = query + ((size_t)b * LQ_ + (size_t)part * 1024) * 256 + c;

        float w[9];
#pragma unroll
        for (int i = 0; i < 9; ++i) w[i] = wp[i];

        float v[6][6];
#pragma unroll
        for (int iy = 0; iy < 6; ++iy) {
            int yy = y0 - 1 + iy;
#pragma unroll
            for (int ix = 0; ix < 6; ++ix) {
                int xx = x0 - 1 + ix;
                bool ok = ((unsigned)yy < 32u) && ((unsigned)xx < 32u);
                v[iy][ix] = ok ? qb[(size_t)(yy * 32 + xx) * 256] : 0.f;
            }
        }
        int gi = part * 256 + c;
        float inv = gq[gi] * rsqrtf(vq[gi] + EPS_);
        float sh  = bq[gi] - mq[gi] * inv;
#pragma unroll
        for (int yi = 0; yi < 4; ++yi) {
#pragma unroll
            for (int xi = 0; xi < 4; ++xi) {
                float acc = 0.f;
#pragma unroll
                for (int ky = 0; ky < 3; ++ky)
#pragma unroll
                    for (int kj = 0; kj < 3; ++kj)
                        acc = fmaf(w[ky * 3 + kj], v[yi + ky][xi + kj], acc);
                int l = part * 1024 + (y0 + yi) * 32 + x0 + xi;
                q_tok[((size_t)b * LQ_ + l) * 256 + c] = (__bf16)fmaf(acc, inv, sh);
            }
        }
    } else if (blk < 1792) {
        // ---- conv_kv: one block per (c, b); computes BOTH K and V convs ----
        int idx = blk - 768;
        int c = idx & 255, b = idx >> 8;
        const float* xp = x + ((size_t)b * 256 + c) * RES_;
#pragma unroll
        for (int i = 0; i < 4; ++i) plane[tid + i * 256] = xp[tid + i * 256];
        __syncthreads();

        const float* wpk = wk + (size_t)c * 9;
        const float* wpv = wv + (size_t)c * 9;
        float wkr[9], wvr[9];
#pragma unroll
        for (int i = 0; i < 9; ++i) { wkr[i] = wpk[i]; wvr[i] = wpv[i]; }
        float invK = gk[c] * rsqrtf(vk[c] + EPS_);
        float shK  = bk[c] - mk[c] * invK;
        float invV = gv[c] * rsqrtf(vv[c] + EPS_);
        float shV  = bv[c] - mv[c] * invV;
        __bf16* outK = k_tok + ((size_t)b * 256 + c) * RES_;
        __bf16* outV = v_tok + ((size_t)b * 256 + c) * RES_;
#pragma unroll
        for (int i0 = 0; i0 < 4; ++i0) {
            int p = tid + i0 * 256;
            int y = p >> 5, xx = p & 31;
            float aK = 0.f, aV = 0.f;
#pragma unroll
            for (int ky = 0; ky < 3; ++ky) {
                int yy = y + ky - 1;
                if ((unsigned)yy >= 32u) continue;
#pragma unroll
                for (int kx = 0; kx < 3; ++kx) {
                    int x2 = xx + kx - 1;
                    if ((unsigned)x2 >= 32u) continue;
                    float pv = plane[yy * 32 + x2];
                    aK = fmaf(wkr[ky * 3 + kx], pv, aK);
                    aV = fmaf(wvr[ky * 3 + kx], pv, aV);
                }
            }
            outK[p] = (__bf16)fmaf(aK, invK, shK);
            outV[p] = (__bf16)fmaf(aV, invV, shV);
        }
    } else {
        // ---- weight f32 -> bf16 ----
        int idx = blk - 1792;
        int m = idx >> 6;
        const float* s = m == 0 ? pw0 : m == 1 ? pw1 : m == 2 ? pw2 : pw3;
        __bf16*      d = m == 0 ? Wq  : m == 1 ? Wk  : m == 2 ? Wv  : Wo;
        int i = ((idx & 63) * 256 + tid) * 4;
        float4 v = *(const float4*)(s + i);
        ushort4 u;
        u.x = bfbits(v.x); u.y = bfbits(v.y); u.z = bfbits(v.z); u.w = bfbits(v.w);
        *(ushort4*)(d + i) = u;
    }
}

// ---------------------------------------------------------------------------
// K and V projection GEMMs. One 32x32 tile per wave.
// ---------------------------------------------------------------------------
__global__ __launch_bounds__(256) void gemm_kv_kernel(
    const __bf16* __restrict__ kt, const __bf16* __restrict__ vt,
    const __bf16* __restrict__ Wk, const __bf16* __restrict__ Wv,
    __bf16* __restrict__ Kb, __bf16* __restrict__ VT)
{
    int tid = threadIdx.x, lane = tid & 63, l31 = lane & 31, hi = lane >> 5;
    int gid = blockIdx.x * 4 + (tid >> 6);

    f32x16 acc;
#pragma unroll
    for (int r = 0; r < 16; ++r) acc[r] = 0.f;

    if (gid < 1024) {
        int g = gid;
        int b = g >> 8, rem = g & 255;
        int j0 = (rem >> 3) * 32, i0 = (rem & 7) * 32;
        const __bf16* Bbase = kt + (size_t)b * 256 * RES_ + j0 + l31;
        const __bf16* Ap = Wk + (size_t)(i0 + l31) * 256 + 8 * hi;
#pragma unroll
        for (int k0 = 0; k0 < 256; k0 += 16) {
            bf16x8 bfr;
#pragma unroll
            for (int jj = 0; jj < 8; ++jj)
                bfr[jj] = Bbase[(size_t)(k0 + 8 * hi + jj) * RES_];
            acc = __builtin_amdgcn_mfma_f32_32x32x16_bf16(
                *(const bf16x8*)(Ap + k0), bfr, acc, 0, 0, 0);
        }
        int head = i0 >> 5;
        __bf16* op = Kb + ((size_t)(b * HEADS_ + head) * RES_ + j0 + l31) * 32 + 4 * hi;
#pragma unroll
        for (int rr = 0; rr < 4; ++rr) {
            ushort4 u;
            u.x = bfbits(acc[4 * rr + 0]); u.y = bfbits(acc[4 * rr + 1]);
            u.z = bfbits(acc[4 * rr + 2]); u.w = bfbits(acc[4 * rr + 3]);
            *(ushort4*)(op + 8 * rr) = u;
        }
    } else {
        int g = gid - 1024;
        int b = g >> 8, rem = g & 255;
        int i0t = (rem >> 3) * 32, j0 = (rem & 7) * 32;
        const __bf16* Abase = vt + (size_t)b * 256 * RES_ + i0t + l31;
        const __bf16* Bp = Wv + (size_t)(j0 + l31) * 256 + 8 * hi;
#pragma unroll
        for (int k0 = 0; k0 < 256; k0 += 16) {
            bf16x8 afr;
#pragma unroll
            for (int jj = 0; jj < 8; ++jj)
                afr[jj] = Abase[(size_t)(k0 + 8 * hi + jj) * RES_];
            acc = __builtin_amdgcn_mfma_f32_32x32x16_bf16(
                afr, *(const bf16x8*)(Bp + k0), acc, 0, 0, 0);
        }
        int head = j0 >> 5;
        __bf16* op = VT + ((size_t)(b * HEADS_ + head) * 32 + l31) * RES_ + i0t + 4 * hi;
#pragma unroll
        for (int rr = 0; rr < 4; ++rr) {
            ushort4 u;
            u.x = bfbits(acc[4 * rr + 0]); u.y = bfbits(acc[4 * rr + 1]);
            u.z = bfbits(acc[4 * rr + 2]); u.w = bfbits(acc[4 * rr + 3]);
            *(ushort4*)(op + 8 * rr) = u;
        }
    }
}

// ---------------------------------------------------------------------------
// Final projection: D[n][l] = Wo . Oc^T + bias. One 32x32 tile per wave.
// ---------------------------------------------------------------------------
__global__ __launch_bounds__(256) void gemm_out_kernel(
    const __bf16* __restrict__ Oc, const __bf16* __restrict__ Wo,
    const float* __restrict__ bias, float* __restrict__ out)
{
    int tid = threadIdx.x, lane = tid & 63, l31 = lane & 31, hi = lane >> 5;
    int gid = blockIdx.x * 4 + (tid >> 6);
    int b = gid / 768, rem = gid % 768;
    int j0 = (rem >> 3) * 32, i0 = (rem & 7) * 32;
    const __bf16* Bp = Oc + ((size_t)b * LQ_ + j0 + l31) * 256 + 8 * hi;
    const __bf16* Ap = Wo + (size_t)(i0 + l31) * 256 + 8 * hi;

    f32x16 acc;
#pragma unroll
    for (int r = 0; r < 16; ++r) acc[r] = 0.f;
#pragma unroll
    for (int k0 = 0; k0 < 256; k0 += 16) {
        acc = __builtin_amdgcn_mfma_f32_32x32x16_bf16(
            *(const bf16x8*)(Ap + k0), *(const bf16x8*)(Bp + k0), acc, 0, 0, 0);
    }
    float* op = out + ((size_t)b * LQ_ + j0 + l31) * 256 + i0 + 4 * hi;
#pragma unroll
    for (int rr = 0; rr < 4; ++rr) {
        float4 bv = *(const float4*)(bias + i0 + 4 * hi + 8 * rr);
        float4 r4;
        r4.x = acc[4 * rr + 0] + bv.x; r4.y = acc[4 * rr + 1] + bv.y;
        r4.z = acc[4 * rr + 2] + bv.z; r4.w = acc[4 * rr + 3] + bv.w;
        *(float4*)(op + 8 * rr) = r4;
    }
}

// ---------------------------------------------------------------------------
// MFMA flash attention v11 = R10's proven v7 single-chunk loop (VGPR 76,
// no spill at (256,4)) + Qlds overlaid on Os (LDS 32,256 -> 26,880 B =>
// 6 blocks/CU, full 1536-block grid co-resident).
// ---------------------------------------------------------------------------
__global__ __launch_bounds__(256, 4) void attn_mfma_kernel(
    const __bf16* __restrict__ qt, const __bf16* __restrict__ Wq,
    const __bf16* __restrict__ Kb, const __bf16* __restrict__ VT,
    __bf16* __restrict__ Oc)
{
    __shared__ float Os[3][64][35];              // 26,880 B
    __bf16* Qlds = (__bf16*)&Os[0][0][0];        // overlay: [64 rows][40 cols]

    int tid  = threadIdx.x;
    int lane = tid & 63, l31 = lane & 31, hi = lane >> 5;
    int th   = tid >> 6;                    // t-quarter 0..3

    int i    = blockIdx.x;
    int xcd  = i & 7, slot = i >> 3;
    int bh   = xcd * 4 + slot / 48;
    int q0   = (slot % 48) * 64;
    int b    = bh >> 3, h = bh & 7;

    // ---- Q projection prologue (waves 0,1) ----
    if (th < 2) {
        const __bf16* Bp = qt + ((size_t)b * LQ_ + q0 + th * 32 + l31) * 256 + 8 * hi;
        const __bf16* Ap = Wq + (size_t)(h * 32 + l31) * 256 + 8 * hi;
        f32x16 acc;
#pragma unroll
        for (int r = 0; r < 16; ++r) acc[r] = 0.f;
#pragma unroll
        for (int k0 = 0; k0 < 256; k0 += 16) {
            acc = __builtin_amdgcn_mfma_f32_32x32x16_bf16(
                *(const bf16x8*)(Ap + k0), *(const bf16x8*)(Bp + k0), acc, 0, 0, 0);
        }
        const float scale = 0.0625f * 1.44269504f;   // 256^-0.5 * log2(e)
        __bf16* qp = Qlds + (size_t)(th * 32 + l31) * 40 + 4 * hi;
#pragma unroll
        for (int rr = 0; rr < 4; ++rr) {
            ushort4 u;
            u.x = bfbits(acc[4 * rr + 0] * scale); u.y = bfbits(acc[4 * rr + 1] * scale);
            u.z = bfbits(acc[4 * rr + 2] * scale); u.w = bfbits(acc[4 * rr + 3] * scale);
            *(ushort4*)(qp + 8 * rr) = u;
        }
    }
    __syncthreads();

    const __bf16* qbase = Qlds + (size_t)l31 * 40 + 8 * hi;
    bf16x8 qA0 = *(const bf16x8*)qbase;
    bf16x8 qA1 = *(const bf16x8*)(qbase + 16);
    bf16x8 qB0 = *(const bf16x8*)(qbase + 32 * 40);
    bf16x8 qB1 = *(const bf16x8*)(qbase + 32 * 40 + 16);
    __syncthreads();   // Qlds fully consumed; Os overlay now safe to write

    const __bf16* kp = Kb + ((size_t)bh * RES_ + th * 256 + l31) * 32 + 8 * hi;
    const __bf16* vp = VT + ((size_t)bh * 32 + l31) * RES_ + th * 256 + 8 * hi;

    f32x16 oA, oB;
#pragma unroll
    for (int r = 0; r < 16; ++r) { oA[r] = 0.f; oB[r] = 0.f; }
    float lsA = 0.f, lsB = 0.f;

    auto smpack = [&](const f32x16& s, float& ls, bf16x8& pb1, bf16x8& pb2) {
        float p[16];
#pragma unroll
        for (int r = 0; r < 16; ++r) p[r] = EXP2(s[r]);

        unsigned int w0 = pkbf(p[0],  p[1]),  w1 = pkbf(p[2],  p[3]);
        unsigned int w2 = pkbf(p[4],  p[5]),  w3 = pkbf(p[6],  p[7]);
        unsigned int w4 = pkbf(p[8],  p[9]),  w5 = pkbf(p[10], p[11]);
        unsigned int w6 = pkbf(p[12], p[13]), w7 = pkbf(p[14], p[15]);

        asm("v_permlane32_swap_b32 %0, %1" : "+v"(w0), "+v"(w2));
        asm("v_permlane32_swap_b32 %0, %1" : "+v"(w1), "+v"(w3));
        asm("v_permlane32_swap_b32 %0, %1" : "+v"(w4), "+v"(w6));
        asm("v_permlane32_swap_b32 %0, %1" : "+v"(w5), "+v"(w7));

        uint4e b1 = { w0, w1, w2, w3 };
        uint4e b2 = { w4, w5, w6, w7 };
        pb1 = __builtin_bit_cast(bf16x8, b1);
        pb2 = __builtin_bit_cast(bf16x8, b2);

        float t0 = (p[0]+p[1]) + (p[2]+p[3]);
        float t1 = (p[4]+p[5]) + (p[6]+p[7]);
        float t2 = (p[8]+p[9]) + (p[10]+p[11]);
        float t3 = (p[12]+p[13]) + (p[14]+p[15]);
        ls += (t0 + t1) + (t2 + t3);
    };

    bf16x8 kc0 = *(const bf16x8*)kp;
    bf16x8 kc1 = *(const bf16x8*)(kp + 16);

#pragma unroll
    for (int st = 0; st < 8; ++st) {
        const __bf16* vc = vp + (size_t)st * 32;
        bf16x8 V0 = *(const bf16x8*)vc;
        bf16x8 V1 = *(const bf16x8*)(vc + 16);

        bf16x8 kn0, kn1;
        if (st < 7) {
            const __bf16* kn = kp + (size_t)(st + 1) * 1024;
            kn0 = *(const bf16x8*)kn;
            kn1 = *(const bf16x8*)(kn + 16);
        }

        f32x16 sA, sB;
#pragma unroll
        for (int r = 0; r < 16; ++r) { sA[r] = 0.f; sB[r] = 0.f; }
        __builtin_amdgcn_s_setprio(1);
        sA = __builtin_amdgcn_mfma_f32_32x32x16_bf16(kc0, qA0, sA, 0, 0, 0);
        sB = __builtin_amdgcn_mfma_f32_32x32x16_bf16(kc0, qB0, sB, 0, 0, 0);
        sA = __builtin_amdgcn_mfma_f32_32x32x16_bf16(kc1, qA1, sA, 0, 0, 0);
        sB = __builtin_amdgcn_mfma_f32_32x32x16_bf16(kc1, qB1, sB, 0, 0, 0);
        __builtin_amdgcn_s_setprio(0);

        bf16x8 pA1, pA2, pB1, pB2;
        smpack(sA, lsA, pA1, pA2);
        smpack(sB, lsB, pB1, pB2);

        __builtin_amdgcn_s_setprio(1);
        oA = __builtin_amdgcn_mfma_f32_32x32x16_bf16(V0, pA1, oA, 0, 0, 0);
        oB = __builtin_amdgcn_mfma_f32_32x32x16_bf16(V0, pB1, oB, 0, 0, 0);
        oA = __builtin_amdgcn_mfma_f32_32x32x16_bf16(V1, pA2, oA, 0, 0, 0);
        oB = __builtin_amdgcn_mfma_f32_32x32x16_bf16(V1, pB2, oB, 0, 0, 0);
        __builtin_amdgcn_s_setprio(0);

        if (st < 7) { kc0 = kn0; kc1 = kn1; }
    }

    lsA += __shfl_xor(lsA, 32, 64);
    lsB += __shfl_xor(lsB, 32, 64);

    // ---- one-stage merge: th>=1 publish, th==0 combines ----
    if (th) {
#pragma unroll
        for (int r = 0; r < 16; ++r) {
            Os[th - 1][lane][r]      = oA[r];
            Os[th - 1][lane][17 + r] = oB[r];
        }
        Os[th - 1][lane][16] = lsA;
        Os[th - 1][lane][33] = lsB;
    }
    __syncthreads();
    if (!th) {
        float lA = lsA + Os[0][lane][16] + Os[1][lane][16] + Os[2][lane][16];
        float lB = lsB + Os[0][lane][33] + Os[1][lane][33] + Os[2][lane][33];
        float invA = 1.0f / lA, invB = 1.0f / lB;
        __bf16* opA = Oc + ((size_t)b * LQ_ + q0 + l31) * 256 + h * 32 + 4 * hi;
        __bf16* opB = opA + (size_t)32 * 256;
#pragma unroll
        for (int rr = 0; rr < 4; ++rr) {
            ushort4 ua, ub;
            ua.x = bfbits((oA[4*rr+0] + Os[0][lane][4*rr+0] + Os[1][lane][4*rr+0] + Os[2][lane][4*rr+0]) * invA);
            ua.y = bfbits((oA[4*rr+1] + Os[0][lane][4*rr+1] + Os[1][lane][4*rr+1] + Os[2][lane][4*rr+1]) * invA);
            ua.z = bfbits((oA[4*rr+2] + Os[0][lane][4*rr+2] + Os[1][lane][4*rr+2] + Os[2][lane][4*rr+2]) * invA);
            ua.w = bfbits((oA[4*rr+3] + Os[0][lane][4*rr+3] + Os[1][lane][4*rr+3] + Os[2][lane][4*rr+3]) * invA);
            ub.x = bfbits((oB[4*rr+0] + Os[0][lane][17+4*rr+0] + Os[1][lane][17+4*rr+0] + Os[2][lane][17+4*rr+0]) * invB);
            ub.y = bfbits((oB[4*rr+1] + Os[0][lane][17+4*rr+1] + Os[1][lane][17+4*rr+1] + Os[2][lane][17+4*rr+1]) * invB);
            ub.z = bfbits((oB[4*rr+2] + Os[0][lane][17+4*rr+2] + Os[1][lane][17+4*rr+2] + Os[2][lane][17+4*rr+2]) * invB);
            ub.w = bfbits((oB[4*rr+3] + Os[0][lane][17+4*rr+3] + Os[1][lane][17+4*rr+3] + Os[2][lane][17+4*rr+3]) * invB);
            *(ushort4*)(opA + 8 * rr) = ua;
            *(ushort4*)(opB + 8 * rr) = ub;
        }
    }
}

// ---------------------------------------------------------------------------
extern "C" void kernel_launch(void* const* d_in, const int* in_sizes, int n_in,
                              void* d_out, int out_size, void* d_ws, size_t ws_size,
                              hipStream_t stream) {
    const float* x        = (const float*)d_in[0];
    const float* query    = (const float*)d_in[1];
    const float* conv_q_w = (const float*)d_in[2];
    const float* bn_q_g   = (const float*)d_in[3];
    const float* bn_q_b   = (const float*)d_in[4];
    const float* bn_q_m   = (const float*)d_in[5];
    const float* bn_q_v   = (const float*)d_in[6];
    const float* conv_k_w = (const float*)d_in[7];
    const float* bn_k_g   = (const float*)d_in[8];
    const float* bn_k_b   = (const float*)d_in[9];
    const float* bn_k_m   = (const float*)d_in[10];
    const float* bn_k_v   = (const float*)d_in[11];
    const float* conv_v_w = (const float*)d_in[12];
    const float* bn_v_g   = (const float*)d_in[13];
    const float* bn_v_b   = (const float*)d_in[14];
    const float* bn_v_m   = (const float*)d_in[15];
    const float* bn_v_v   = (const float*)d_in[16];
    const float* proj_q_w = (const float*)d_in[17];
    const float* proj_k_w = (const float*)d_in[18];
    const float* proj_v_w = (const float*)d_in[19];
    const float* proj_w   = (const float*)d_in[20];
    const float* proj_b   = (const float*)d_in[21];

    char* ws = (char*)d_ws;
    __bf16* q_tok = (__bf16*)(ws + 0);          //  6,291,456 B
    __bf16* k_tok = (__bf16*)(ws + 6291456);    //  2,097,152 B
    __bf16* v_tok = (__bf16*)(ws + 8388608);    //  2,097,152 B
    __bf16* Kb    = (__bf16*)(ws + 10485760);   //  2,097,152 B
    __bf16* VT    = (__bf16*)(ws + 12582912);   //  2,097,152 B
    __bf16* Wq    = (__bf16*)(ws + 14680064);   //    131,072 B each
    __bf16* Wk    = (__bf16*)(ws + 14811136);
    __bf16* Wv    = (__bf16*)(ws + 14942208);
    __bf16* Wo    = (__bf16*)(ws + 15073280);
    __bf16* Oc    = (__bf16*)(ws + 15204352);   //  6,291,456 B
    float*  out   = (float*)d_out;

    pre_kernel<<<dim3(2048), 256, 0, stream>>>(
        query, x, conv_q_w, bn_q_g, bn_q_b, bn_q_m, bn_q_v,
        conv_k_w, bn_k_g, bn_k_b, bn_k_m, bn_k_v,
        conv_v_w, bn_v_g, bn_v_b, bn_v_m, bn_v_v,
        proj_q_w, proj_k_w, proj_v_w, proj_w,
        q_tok, k_tok, v_tok, Wq, Wk, Wv, Wo);

    gemm_kv_kernel<<<dim3(512), 256, 0, stream>>>(
        k_tok, v_tok, Wk, Wv, Kb, VT);

    attn_mfma_kernel<<<dim3(1536), 256, 0, stream>>>(q_tok, Wq, Kb, VT, Oc);

    gemm_out_kernel<<<dim3(768), 256, 0, stream>>>(Oc, Wo, proj_b, out);
}

// Round 16
// 68.577 us; speedup vs baseline: 2.8846x; 1.0334x over previous
//
#include <hip/hip_runtime.h>
#include <hip/hip_bf16.h>
#include <math.h>

#define B_     4
#define C_     256
#define RES_   1024
#define FEA_   3
#define LQ_    3072
#define HEADS_ 8
#define EPS_   1e-5f

typedef __bf16 bf16x8 __attribute__((ext_vector_type(8)));
typedef float  f32x16 __attribute__((ext_vector_type(16)));
typedef unsigned int uint4e __attribute__((ext_vector_type(4)));

#if __has_builtin(__builtin_amdgcn_exp2f)
#define EXP2(x) __builtin_amdgcn_exp2f(x)
#else
#define EXP2(x) exp2f(x)
#endif

__device__ __forceinline__ unsigned short bfbits(float v) {
    return __builtin_bit_cast(unsigned short, (__bf16)v);
}
__device__ __forceinline__ unsigned int pkbf(float lo, float hi2) {
    return (unsigned int)bfbits(lo) | ((unsigned int)bfbits(hi2) << 16);
}

// ---------------------------------------------------------------------------
// Fused pre-pass:
//   conv_q 4x4-token tiles   [0, 768)
//   conv_kv (K+V fused, one x-plane load, bf16 out)  [768, 1792)
//   weight cvt               [1792, 2048)
// ---------------------------------------------------------------------------
__global__ __launch_bounds__(256) void pre_kernel(
    const float* __restrict__ query, const float* __restrict__ x,
    const float* __restrict__ wq,
    const float* __restrict__ gq, const float* __restrict__ bq,
    const float* __restrict__ mq, const float* __restrict__ vq,
    const float* __restrict__ wk, const float* __restrict__ gk, const float* __restrict__ bk,
    const float* __restrict__ mk, const float* __restrict__ vk,
    const float* __restrict__ wv, const float* __restrict__ gv, const float* __restrict__ bv,
    const float* __restrict__ mv, const float* __restrict__ vv,
    const float* __restrict__ pw0, const float* __restrict__ pw1,
    const float* __restrict__ pw2, const float* __restrict__ pw3,
    __bf16* __restrict__ q_tok, __bf16* __restrict__ k_tok, __bf16* __restrict__ v_tok,
    __bf16* __restrict__ Wq, __bf16* __restrict__ Wk,
    __bf16* __restrict__ Wv, __bf16* __restrict__ Wo)
{
    __shared__ float plane[RES_];
    int blk = blockIdx.x, tid = threadIdx.x;

    if (blk < 768) {
        // ---- conv_q: one block per (b, part, 4x4 tile); thread = channel ----
        int b = blk / 192, rem = blk % 192;
        int part = rem >> 6, t = rem & 63;
        int y0 = (t >> 3) * 4, x0 = (t & 7) * 4;
        int c = tid;
        const float* wp = wq + (size_t)(part * 256 + c) * 9;
        const float* qb = query + ((size_t)b * LQ_ + (size_t)part * 1024) * 256 + c;

        float w[9];
#pragma unroll
        for (int i = 0; i < 9; ++i) w[i] = wp[i];

        float v[6][6];
#pragma unroll
        for (int iy = 0; iy < 6; ++iy) {
            int yy = y0 - 1 + iy;
#pragma unroll
            for (int ix = 0; ix < 6; ++ix) {
                int xx = x0 - 1 + ix;
                bool ok = ((unsigned)yy < 32u) && ((unsigned)xx < 32u);
                v[iy][ix] = ok ? qb[(size_t)(yy * 32 + xx) * 256] : 0.f;
            }
        }
        int gi = part * 256 + c;
        float inv = gq[gi] * rsqrtf(vq[gi] + EPS_);
        float sh  = bq[gi] - mq[gi] * inv;
#pragma unroll
        for (int yi = 0; yi < 4; ++yi) {
#pragma unroll
            for (int xi = 0; xi < 4; ++xi) {
                float acc = 0.f;
#pragma unroll
                for (int ky = 0; ky < 3; ++ky)
#pragma unroll
                    for (int kj = 0; kj < 3; ++kj)
                        acc = fmaf(w[ky * 3 + kj], v[yi + ky][xi + kj], acc);
                int l = part * 1024 + (y0 + yi) * 32 + x0 + xi;
                q_tok[((size_t)b * LQ_ + l) * 256 + c] = (__bf16)fmaf(acc, inv, sh);
            }
        }
    } else if (blk < 1792) {
        // ---- conv_kv: one block per (c, b); computes BOTH K and V convs ----
        int idx = blk - 768;
        int c = idx & 255, b = idx >> 8;
        const float* xp = x + ((size_t)b * 256 + c) * RES_;
#pragma unroll
        for (int i = 0; i < 4; ++i) plane[tid + i * 256] = xp[tid + i * 256];
        __syncthreads();

        const float* wpk = wk + (size_t)c * 9;
        const float* wpv = wv + (size_t)c * 9;
        float wkr[9], wvr[9];
#pragma unroll
        for (int i = 0; i < 9; ++i) { wkr[i] = wpk[i]; wvr[i] = wpv[i]; }
        float invK = gk[c] * rsqrtf(vk[c] + EPS_);
        float shK  = bk[c] - mk[c] * invK;
        float invV = gv[c] * rsqrtf(vv[c] + EPS_);
        float shV  = bv[c] - mv[c] * invV;
        __bf16* outK = k_tok + ((size_t)b * 256 + c) * RES_;
        __bf16* outV = v_tok + ((size_t)b * 256 + c) * RES_;
#pragma unroll
        for (int i0 = 0; i0 < 4; ++i0) {
            int p = tid + i0 * 256;
            int y = p >> 5, xx = p & 31;
            float aK = 0.f, aV = 0.f;
#pragma unroll
            for (int ky = 0; ky < 3; ++ky) {
                int yy = y + ky - 1;
                if ((unsigned)yy >= 32u) continue;
#pragma unroll
                for (int kx = 0; kx < 3; ++kx) {
                    int x2 = xx + kx - 1;
                    if ((unsigned)x2 >= 32u) continue;
                    float pv = plane[yy * 32 + x2];
                    aK = fmaf(wkr[ky * 3 + kx], pv, aK);
                    aV = fmaf(wvr[ky * 3 + kx], pv, aV);
                }
            }
            outK[p] = (__bf16)fmaf(aK, invK, shK);
            outV[p] = (__bf16)fmaf(aV, invV, shV);
        }
    } else {
        // ---- weight f32 -> bf16 ----
        int idx = blk - 1792;
        int m = idx >> 6;
        const float* s = m == 0 ? pw0 : m == 1 ? pw1 : m == 2 ? pw2 : pw3;
        __bf16*      d = m == 0 ? Wq  : m == 1 ? Wk  : m == 2 ? Wv  : Wo;
        int i = ((idx & 63) * 256 + tid) * 4;
        float4 v = *(const float4*)(s + i);
        ushort4 u;
        u.x = bfbits(v.x); u.y = bfbits(v.y); u.z = bfbits(v.z); u.w = bfbits(v.w);
        *(ushort4*)(d + i) = u;
    }
}

// ---------------------------------------------------------------------------
// K and V projection GEMMs. One 32x32 tile per wave.
// K: D[d][t] -> Kb [bh][t][32]
// V: D[t][d] -> VTt [bh][t/32][d=32][t%32]  (tiled: coalesced write AND read)
// ---------------------------------------------------------------------------
__global__ __launch_bounds__(256) void gemm_kv_kernel(
    const __bf16* __restrict__ kt, const __bf16* __restrict__ vt,
    const __bf16* __restrict__ Wk, const __bf16* __restrict__ Wv,
    __bf16* __restrict__ Kb, __bf16* __restrict__ VTt)
{
    int tid = threadIdx.x, lane = tid & 63, l31 = lane & 31, hi = lane >> 5;
    int gid = blockIdx.x * 4 + (tid >> 6);

    f32x16 acc;
#pragma unroll
    for (int r = 0; r < 16; ++r) acc[r] = 0.f;

    if (gid < 1024) {
        int g = gid;
        int b = g >> 8, rem = g & 255;
        int j0 = (rem >> 3) * 32, i0 = (rem & 7) * 32;
        const __bf16* Bbase = kt + (size_t)b * 256 * RES_ + j0 + l31;
        const __bf16* Ap = Wk + (size_t)(i0 + l31) * 256 + 8 * hi;
#pragma unroll
        for (int k0 = 0; k0 < 256; k0 += 16) {
            bf16x8 bfr;
#pragma unroll
            for (int jj = 0; jj < 8; ++jj)
                bfr[jj] = Bbase[(size_t)(k0 + 8 * hi + jj) * RES_];
            acc = __builtin_amdgcn_mfma_f32_32x32x16_bf16(
                *(const bf16x8*)(Ap + k0), bfr, acc, 0, 0, 0);
        }
        int head = i0 >> 5;
        __bf16* op = Kb + ((size_t)(b * HEADS_ + head) * RES_ + j0 + l31) * 32 + 4 * hi;
#pragma unroll
        for (int rr = 0; rr < 4; ++rr) {
            ushort4 u;
            u.x = bfbits(acc[4 * rr + 0]); u.y = bfbits(acc[4 * rr + 1]);
            u.z = bfbits(acc[4 * rr + 2]); u.w = bfbits(acc[4 * rr + 3]);
            *(ushort4*)(op + 8 * rr) = u;
        }
    } else {
        int g = gid - 1024;
        int b = g >> 8, rem = g & 255;
        int i0t = (rem >> 3) * 32, j0 = (rem & 7) * 32;   // i0t: t-tile base, j0: d (head)
        const __bf16* Abase = vt + (size_t)b * 256 * RES_ + i0t + l31;
        const __bf16* Bp = Wv + (size_t)(j0 + l31) * 256 + 8 * hi;
#pragma unroll
        for (int k0 = 0; k0 < 256; k0 += 16) {
            bf16x8 afr;
#pragma unroll
            for (int jj = 0; jj < 8; ++jj)
                afr[jj] = Abase[(size_t)(k0 + 8 * hi + jj) * RES_];
            acc = __builtin_amdgcn_mfma_f32_32x32x16_bf16(
                afr, *(const bf16x8*)(Bp + k0), acc, 0, 0, 0);
        }
        int head = j0 >> 5;
        // D rows = t (tlocal = (reg&3) + 8*(reg>>2) + 4*hi), cols = d = l31.
        // Tiled store: VTt[((bh*32 + i0t/32)*32 + d)*32 + tlocal]
        __bf16* op = VTt + (((size_t)(b * HEADS_ + head) * 32 + (i0t >> 5)) * 32 + l31) * 32 + 4 * hi;
#pragma unroll
        for (int rr = 0; rr < 4; ++rr) {
            ushort4 u;
            u.x = bfbits(acc[4 * rr + 0]); u.y = bfbits(acc[4 * rr + 1]);
            u.z = bfbits(acc[4 * rr + 2]); u.w = bfbits(acc[4 * rr + 3]);
            *(ushort4*)(op + 8 * rr) = u;
        }
    }
}

// ---------------------------------------------------------------------------
// Final projection: D[n][l] = Wo . Oc^T + bias. One 32x32 tile per wave.
// ---------------------------------------------------------------------------
__global__ __launch_bounds__(256) void gemm_out_kernel(
    const __bf16* __restrict__ Oc, const __bf16* __restrict__ Wo,
    const float* __restrict__ bias, float* __restrict__ out)
{
    int tid = threadIdx.x, lane = tid & 63, l31 = lane & 31, hi = lane >> 5;
    int gid = blockIdx.x * 4 + (tid >> 6);
    int b = gid / 768, rem = gid % 768;
    int j0 = (rem >> 3) * 32, i0 = (rem & 7) * 32;
    const __bf16* Bp = Oc + ((size_t)b * LQ_ + j0 + l31) * 256 + 8 * hi;
    const __bf16* Ap = Wo + (size_t)(i0 + l31) * 256 + 8 * hi;

    f32x16 acc;
#pragma unroll
    for (int r = 0; r < 16; ++r) acc[r] = 0.f;
#pragma unroll
    for (int k0 = 0; k0 < 256; k0 += 16) {
        acc = __builtin_amdgcn_mfma_f32_32x32x16_bf16(
            *(const bf16x8*)(Ap + k0), *(const bf16x8*)(Bp + k0), acc, 0, 0, 0);
    }
    float* op = out + ((size_t)b * LQ_ + j0 + l31) * 256 + i0 + 4 * hi;
#pragma unroll
    for (int rr = 0; rr < 4; ++rr) {
        float4 bv = *(const float4*)(bias + i0 + 4 * hi + 8 * rr);
        float4 r4;
        r4.x = acc[4 * rr + 0] + bv.x; r4.y = acc[4 * rr + 1] + bv.y;
        r4.z = acc[4 * rr + 2] + bv.z; r4.w = acc[4 * rr + 3] + bv.w;
        *(float4*)(op + 8 * rr) = r4;
    }
}

// ---------------------------------------------------------------------------
// MFMA flash attention v12 = R15 (proven) with tiled-VTt reads:
// V fragment loads are now fully coalesced (wave covers one contiguous 2 KB
// block per load instead of a 32-cache-line gather over 64 KB).
// ---------------------------------------------------------------------------
__global__ __launch_bounds__(256, 4) void attn_mfma_kernel(
    const __bf16* __restrict__ qt, const __bf16* __restrict__ Wq,
    const __bf16* __restrict__ Kb, const __bf16* __restrict__ VTt,
    __bf16* __restrict__ Oc)
{
    __shared__ float Os[3][64][35];              // 26,880 B
    __bf16* Qlds = (__bf16*)&Os[0][0][0];        // overlay: [64 rows][40 cols]

    int tid  = threadIdx.x;
    int lane = tid & 63, l31 = lane & 31, hi = lane >> 5;
    int th   = tid >> 6;                    // t-quarter 0..3

    int i    = blockIdx.x;
    int xcd  = i & 7, slot = i >> 3;
    int bh   = xcd * 4 + slot / 48;
    int q0   = (slot % 48) * 64;
    int b    = bh >> 3, h = bh & 7;

    // ---- Q projection prologue (waves 0,1) ----
    if (th < 2) {
        const __bf16* Bp = qt + ((size_t)b * LQ_ + q0 + th * 32 + l31) * 256 + 8 * hi;
        const __bf16* Ap = Wq + (size_t)(h * 32 + l31) * 256 + 8 * hi;
        f32x16 acc;
#pragma unroll
        for (int r = 0; r < 16; ++r) acc[r] = 0.f;
#pragma unroll
        for (int k0 = 0; k0 < 256; k0 += 16) {
            acc = __builtin_amdgcn_mfma_f32_32x32x16_bf16(
                *(const bf16x8*)(Ap + k0), *(const bf16x8*)(Bp + k0), acc, 0, 0, 0);
        }
        const float scale = 0.0625f * 1.44269504f;   // 256^-0.5 * log2(e)
        __bf16* qp = Qlds + (size_t)(th * 32 + l31) * 40 + 4 * hi;
#pragma unroll
        for (int rr = 0; rr < 4; ++rr) {
            ushort4 u;
            u.x = bfbits(acc[4 * rr + 0] * scale); u.y = bfbits(acc[4 * rr + 1] * scale);
            u.z = bfbits(acc[4 * rr + 2] * scale); u.w = bfbits(acc[4 * rr + 3] * scale);
            *(ushort4*)(qp + 8 * rr) = u;
        }
    }
    __syncthreads();

    const __bf16* qbase = Qlds + (size_t)l31 * 40 + 8 * hi;
    bf16x8 qA0 = *(const bf16x8*)qbase;
    bf16x8 qA1 = *(const bf16x8*)(qbase + 16);
    bf16x8 qB0 = *(const bf16x8*)(qbase + 32 * 40);
    bf16x8 qB1 = *(const bf16x8*)(qbase + 32 * 40 + 16);
    __syncthreads();   // Qlds fully consumed; Os overlay now safe to write

    const __bf16* kp = Kb + ((size_t)bh * RES_ + th * 256 + l31) * 32 + 8 * hi;
    // tiled V: tile index = th*8 + st; lane element = l31*32 + 8*hi (+16 for V1)
    const __bf16* vp = VTt + (((size_t)bh * 32 + th * 8) * 32 + l31) * 32 + 8 * hi;

    f32x16 oA, oB;
#pragma unroll
    for (int r = 0; r < 16; ++r) { oA[r] = 0.f; oB[r] = 0.f; }
    float lsA = 0.f, lsB = 0.f;

    auto smpack = [&](const f32x16& s, float& ls, bf16x8& pb1, bf16x8& pb2) {
        float p[16];
#pragma unroll
        for (int r = 0; r < 16; ++r) p[r] = EXP2(s[r]);

        unsigned int w0 = pkbf(p[0],  p[1]),  w1 = pkbf(p[2],  p[3]);
        unsigned int w2 = pkbf(p[4],  p[5]),  w3 = pkbf(p[6],  p[7]);
        unsigned int w4 = pkbf(p[8],  p[9]),  w5 = pkbf(p[10], p[11]);
        unsigned int w6 = pkbf(p[12], p[13]), w7 = pkbf(p[14], p[15]);

        asm("v_permlane32_swap_b32 %0, %1" : "+v"(w0), "+v"(w2));
        asm("v_permlane32_swap_b32 %0, %1" : "+v"(w1), "+v"(w3));
        asm("v_permlane32_swap_b32 %0, %1" : "+v"(w4), "+v"(w6));
        asm("v_permlane32_swap_b32 %0, %1" : "+v"(w5), "+v"(w7));

        uint4e b1 = { w0, w1, w2, w3 };
        uint4e b2 = { w4, w5, w6, w7 };
        pb1 = __builtin_bit_cast(bf16x8, b1);
        pb2 = __builtin_bit_cast(bf16x8, b2);

        float t0 = (p[0]+p[1]) + (p[2]+p[3]);
        float t1 = (p[4]+p[5]) + (p[6]+p[7]);
        float t2 = (p[8]+p[9]) + (p[10]+p[11]);
        float t3 = (p[12]+p[13]) + (p[14]+p[15]);
        ls += (t0 + t1) + (t2 + t3);
    };

    bf16x8 kc0 = *(const bf16x8*)kp;
    bf16x8 kc1 = *(const bf16x8*)(kp + 16);

#pragma unroll
    for (int st = 0; st < 8; ++st) {
        const __bf16* vc = vp + (size_t)st * 1024;   // next 32x32 V tile
        bf16x8 V0 = *(const bf16x8*)vc;
        bf16x8 V1 = *(const bf16x8*)(vc + 16);

        bf16x8 kn0, kn1;
        if (st < 7) {
            const __bf16* kn = kp + (size_t)(st + 1) * 1024;
            kn0 = *(const bf16x8*)kn;
            kn1 = *(const bf16x8*)(kn + 16);
        }

        f32x16 sA, sB;
#pragma unroll
        for (int r = 0; r < 16; ++r) { sA[r] = 0.f; sB[r] = 0.f; }
        __builtin_amdgcn_s_setprio(1);
        sA = __builtin_amdgcn_mfma_f32_32x32x16_bf16(kc0, qA0, sA, 0, 0, 0);
        sB = __builtin_amdgcn_mfma_f32_32x32x16_bf16(kc0, qB0, sB, 0, 0, 0);
        sA = __builtin_amdgcn_mfma_f32_32x32x16_bf16(kc1, qA1, sA, 0, 0, 0);
        sB = __builtin_amdgcn_mfma_f32_32x32x16_bf16(kc1, qB1, sB, 0, 0, 0);
        __builtin_amdgcn_s_setprio(0);

        bf16x8 pA1, pA2, pB1, pB2;
        smpack(sA, lsA, pA1, pA2);
        smpack(sB, lsB, pB1, pB2);

        __builtin_amdgcn_s_setprio(1);
        oA = __builtin_amdgcn_mfma_f32_32x32x16_bf16(V0, pA1, oA, 0, 0, 0);
        oB = __builtin_amdgcn_mfma_f32_32x32x16_bf16(V0, pB1, oB, 0, 0, 0);
        oA = __builtin_amdgcn_mfma_f32_32x32x16_bf16(V1, pA2, oA, 0, 0, 0);
        oB = __builtin_amdgcn_mfma_f32_32x32x16_bf16(V1, pB2, oB, 0, 0, 0);
        __builtin_amdgcn_s_setprio(0);

        if (st < 7) { kc0 = kn0; kc1 = kn1; }
    }

    lsA += __shfl_xor(lsA, 32, 64);
    lsB += __shfl_xor(lsB, 32, 64);

    // ---- one-stage merge: th>=1 publish, th==0 combines ----
    if (th) {
#pragma unroll
        for (int r = 0; r < 16; ++r) {
            Os[th - 1][lane][r]      = oA[r];
            Os[th - 1][lane][17 + r] = oB[r];
        }
        Os[th - 1][lane][16] = lsA;
        Os[th - 1][lane][33] = lsB;
    }
    __syncthreads();
    if (!th) {
        float lA = lsA + Os[0][lane][16] + Os[1][lane][16] + Os[2][lane][16];
        float lB = lsB + Os[0][lane][33] + Os[1][lane][33] + Os[2][lane][33];
        float invA = 1.0f / lA, invB = 1.0f / lB;
        __bf16* opA = Oc + ((size_t)b * LQ_ + q0 + l31) * 256 + h * 32 + 4 * hi;
        __bf16* opB = opA + (size_t)32 * 256;
#pragma unroll
        for (int rr = 0; rr < 4; ++rr) {
            ushort4 ua, ub;
            ua.x = bfbits((oA[4*rr+0] + Os[0][lane][4*rr+0] + Os[1][lane][4*rr+0] + Os[2][lane][4*rr+0]) * invA);
            ua.y = bfbits((oA[4*rr+1] + Os[0][lane][4*rr+1] + Os[1][lane][4*rr+1] + Os[2][lane][4*rr+1]) * invA);
            ua.z = bfbits((oA[4*rr+2] + Os[0][lane][4*rr+2] + Os[1][lane][4*rr+2] + Os[2][lane][4*rr+2]) * invA);
            ua.w = bfbits((oA[4*rr+3] + Os[0][lane][4*rr+3] + Os[1][lane][4*rr+3] + Os[2][lane][4*rr+3]) * invA);
            ub.x = bfbits((oB[4*rr+0] + Os[0][lane][17+4*rr+0] + Os[1][lane][17+4*rr+0] + Os[2][lane][17+4*rr+0]) * invB);
            ub.y = bfbits((oB[4*rr+1] + Os[0][lane][17+4*rr+1] + Os[1][lane][17+4*rr+1] + Os[2][lane][17+4*rr+1]) * invB);
            ub.z = bfbits((oB[4*rr+2] + Os[0][lane][17+4*rr+2] + Os[1][lane][17+4*rr+2] + Os[2][lane][17+4*rr+2]) * invB);
            ub.w = bfbits((oB[4*rr+3] + Os[0][lane][17+4*rr+3] + Os[1][lane][17+4*rr+3] + Os[2][lane][17+4*rr+3]) * invB);
            *(ushort4*)(opA + 8 * rr) = ua;
            *(ushort4*)(opB + 8 * rr) = ub;
        }
    }
}

// ---------------------------------------------------------------------------
extern "C" void kernel_launch(void* const* d_in, const int* in_sizes, int n_in,
                              void* d_out, int out_size, void* d_ws, size_t ws_size,
                              hipStream_t stream) {
    const float* x        = (const float*)d_in[0];
    const float* query    = (const float*)d_in[1];
    const float* conv_q_w = (const float*)d_in[2];
    const float* bn_q_g   = (const float*)d_in[3];
    const float* bn_q_b   = (const float*)d_in[4];
    const float* bn_q_m   = (const float*)d_in[5];
    const float* bn_q_v   = (const float*)d_in[6];
    const float* conv_k_w = (const float*)d_in[7];
    const float* bn_k_g   = (const float*)d_in[8];
    const float* bn_k_b   = (const float*)d_in[9];
    const float* bn_k_m   = (const float*)d_in[10];
    const float* bn_k_v   = (const float*)d_in[11];
    const float* conv_v_w = (const float*)d_in[12];
    const float* bn_v_g   = (const float*)d_in[13];
    const float* bn_v_b   = (const float*)d_in[14];
    const float* bn_v_m   = (const float*)d_in[15];
    const float* bn_v_v   = (const float*)d_in[16];
    const float* proj_q_w = (const float*)d_in[17];
    const float* proj_k_w = (const float*)d_in[18];
    const float* proj_v_w = (const float*)d_in[19];
    const float* proj_w   = (const float*)d_in[20];
    const float* proj_b   = (const float*)d_in[21];

    char* ws = (char*)d_ws;
    __bf16* q_tok = (__bf16*)(ws + 0);          //  6,291,456 B
    __bf16* k_tok = (__bf16*)(ws + 6291456);    //  2,097,152 B
    __bf16* v_tok = (__bf16*)(ws + 8388608);    //  2,097,152 B
    __bf16* Kb    = (__bf16*)(ws + 10485760);   //  2,097,152 B
    __bf16* VTt   = (__bf16*)(ws + 12582912);   //  2,097,152 B (tiled)
    __bf16* Wq    = (__bf16*)(ws + 14680064);   //    131,072 B each
    __bf16* Wk    = (__bf16*)(ws + 14811136);
    __bf16* Wv    = (__bf16*)(ws + 14942208);
    __bf16* Wo    = (__bf16*)(ws + 15073280);
    __bf16* Oc    = (__bf16*)(ws + 15204352);   //  6,291,456 B
    float*  out   = (float*)d_out;

    pre_kernel<<<dim3(2048), 256, 0, stream>>>(
        query, x, conv_q_w, bn_q_g, bn_q_b, bn_q_m, bn_q_v,
        conv_k_w, bn_k_g, bn_k_b, bn_k_m, bn_k_v,
        conv_v_w, bn_v_g, bn_v_b, bn_v_m, bn_v_v,
        proj_q_w, proj_k_w, proj_v_w, proj_w,
        q_tok, k_tok, v_tok, Wq, Wk, Wv, Wo);

    gemm_kv_kernel<<<dim3(512), 256, 0, stream>>>(
        k_tok, v_tok, Wk, Wv, Kb, VTt);

    attn_mfma_kernel<<<dim3(1536), 256, 0, stream>>>(q_tok, Wq, Kb, VTt, Oc);

    gemm_out_kernel<<<dim3(768), 256, 0, stream>>>(Oc, Wo, proj_b, out);
}